// Round 1
// baseline (1302.566 us; speedup 1.0000x reference)
//
#include <hip/hip_runtime.h>

#define N_NODES 50000
#define N_EDGES 800000
#define DIM 128
#define NT 4
#define NR 6
#define NH 8
#define DKH 16

// ---- order-preserving float<->uint encoding for atomicMax on floats ----
__device__ __forceinline__ unsigned int enc_f(float f) {
    unsigned int u = __float_as_uint(f);
    return (u & 0x80000000u) ? ~u : (u | 0x80000000u);
}
__device__ __forceinline__ float dec_f(unsigned int u) {
    return (u & 0x80000000u) ? __uint_as_float(u ^ 0x80000000u) : __uint_as_float(~u);
}

__device__ __forceinline__ int sign_index(int s) {
    // es = where((s < -1)|(s==0), -2, clip(s,-1,1)); idx: -1->0, 1->1, else->2
    if (s < -1 || s == 0) return 2;
    return (s == -1) ? 0 : 1;
}

// ---------------- bucketing ----------------
__global__ void k_count(const int* __restrict__ ntype, int* __restrict__ counts) {
    int n = blockIdx.x * blockDim.x + threadIdx.x;
    if (n < N_NODES) atomicAdd(&counts[ntype[n]], 1);
}

__global__ void k_offsets(const int* __restrict__ counts, int* __restrict__ cursors) {
    if (blockIdx.x == 0 && threadIdx.x == 0) {
        int acc = 0;
        for (int t = 0; t < NT; ++t) { cursors[t] = acc; acc += counts[t]; }
    }
}

__global__ void k_scatter(const int* __restrict__ ntype, int* __restrict__ cursors,
                          int* __restrict__ order) {
    int n = blockIdx.x * blockDim.x + threadIdx.x;
    if (n < N_NODES) {
        int t = ntype[n];
        int pos = atomicAdd(&cursors[t], 1);
        order[pos] = n;
    }
}

// ---------------- per-type QKV projection ----------------
// block = 128 threads (one output column each), 8 nodes per block (type-bucketed)
__global__ __launch_bounds__(128) void k_proj(
    const float* __restrict__ x, const int* __restrict__ order, const int* __restrict__ ntype,
    const float* __restrict__ Wq, const float* __restrict__ bq,
    const float* __restrict__ Wk, const float* __restrict__ bk,
    const float* __restrict__ Wv, const float* __restrict__ bv,
    float* __restrict__ Q, float* __restrict__ K, float* __restrict__ V)
{
    __shared__ float xs[8][DIM];
    __shared__ int nid[8];
    __shared__ int nts[8];
    const int tid = threadIdx.x;
    const int b = blockIdx.x;
    if (tid < 8) {
        int n = order[b * 8 + tid];
        nid[tid] = n;
        nts[tid] = ntype[n];
    }
    __syncthreads();
    #pragma unroll
    for (int j = 0; j < 8; ++j) xs[j][tid] = x[nid[j] * DIM + tid];
    __syncthreads();

    const int o = tid;
    int t0 = nts[0];
    bool uni = true;
    #pragma unroll
    for (int j = 1; j < 8; ++j) uni = uni && (nts[j] == t0);

    if (uni) {
        const float* wq = Wq + t0 * DIM * DIM;
        const float* wk = Wk + t0 * DIM * DIM;
        const float* wv = Wv + t0 * DIM * DIM;
        float aq[8], ak[8], av[8];
        #pragma unroll
        for (int j = 0; j < 8; ++j) { aq[j] = 0.f; ak[j] = 0.f; av[j] = 0.f; }
        for (int i = 0; i < DIM; ++i) {
            float wqv = wq[i * DIM + o];
            float wkv = wk[i * DIM + o];
            float wvv = wv[i * DIM + o];
            #pragma unroll
            for (int j = 0; j < 8; ++j) {
                float xv = xs[j][i];
                aq[j] = fmaf(xv, wqv, aq[j]);
                ak[j] = fmaf(xv, wkv, ak[j]);
                av[j] = fmaf(xv, wvv, av[j]);
            }
        }
        float bqv = bq[t0 * DIM + o], bkv = bk[t0 * DIM + o], bvv = bv[t0 * DIM + o];
        #pragma unroll
        for (int j = 0; j < 8; ++j) {
            int n = nid[j];
            Q[n * DIM + o] = aq[j] + bqv;
            K[n * DIM + o] = ak[j] + bkv;
            V[n * DIM + o] = av[j] + bvv;
        }
    } else {
        // rare boundary block (types straddle)
        for (int j = 0; j < 8; ++j) {
            int t = nts[j];
            float aq = 0.f, ak = 0.f, av = 0.f;
            for (int i = 0; i < DIM; ++i) {
                float xv = xs[j][i];
                aq = fmaf(xv, Wq[(t * DIM + i) * DIM + o], aq);
                ak = fmaf(xv, Wk[(t * DIM + i) * DIM + o], ak);
                av = fmaf(xv, Wv[(t * DIM + i) * DIM + o], av);
            }
            int n = nid[j];
            Q[n * DIM + o] = aq + bq[t * DIM + o];
            K[n * DIM + o] = ak + bk[t * DIM + o];
            V[n * DIM + o] = av + bv[t * DIM + o];
        }
    }
}

// ---------------- pass 1: edge scores + segment max ----------------
// thread per (edge, head)
__global__ __launch_bounds__(256) void k_pass1(
    const float* __restrict__ Q, const float* __restrict__ K,
    const int* __restrict__ ei, const int* __restrict__ etype,
    const int* __restrict__ esign, const float* __restrict__ edist,
    const float* __restrict__ rel_q, const float* __restrict__ rel_k,
    const float* __restrict__ skn, const float* __restrict__ rbias,
    const float* __restrict__ dalpha, const float* __restrict__ dtau,
    float* __restrict__ scores, unsigned int* __restrict__ m_enc)
{
    int gid = blockIdx.x * 256 + threadIdx.x;
    if (gid >= N_EDGES * NH) return;
    int e = gid >> 3;
    int h = gid & 7;
    int src = ei[e];
    int dst = ei[N_EDGES + e];
    int et = etype[e];
    int sidx = sign_index(esign[e]);

    const float* qp = Q + dst * DIM + h * DKH;
    const float* kp = K + src * DIM + h * DKH;
    const float* rq = rel_q + (et * NH + h) * DKH;
    const float* rk = rel_k + (et * NH + h) * DKH;
    const float* sk = skn + h * DKH;

    float dot = 0.f;
    if (sidx == 2) {
        #pragma unroll
        for (int k = 0; k < DKH; ++k)
            dot = fmaf(qp[k] * rq[k], kp[k] * rk[k] * sk[k], dot);
    } else {
        #pragma unroll
        for (int k = 0; k < DKH; ++k)
            dot = fmaf(qp[k] * rq[k], kp[k] * rk[k], dot);
        if (sidx == 0) dot = -dot;
    }

    float phi = dalpha[0] * expf(-edist[e] / (dtau[0] + 1e-9f));
    float sc = dot * 0.25f + rbias[et * NH + h] + phi;
    scores[gid] = sc;
    atomicMax(m_enc + dst * NH + h, enc_f(sc));
}

// ---------------- pass 2: exp, Z accumulation, weighted-V scatter ----------------
// one wave (64 lanes) per edge; lane covers outputs o=lane and o=lane+64
__global__ __launch_bounds__(256) void k_pass2(
    const float* __restrict__ V,
    const int* __restrict__ ei, const int* __restrict__ etype, const int* __restrict__ esign,
    const float* __restrict__ rel_v, const float* __restrict__ svn,
    const float* __restrict__ scores, const unsigned int* __restrict__ m_enc,
    float* __restrict__ Z, float* __restrict__ out)
{
    int e = blockIdx.x * 4 + (threadIdx.x >> 6);
    if (e >= N_EDGES) return;
    int lane = threadIdx.x & 63;
    int src = ei[e];
    int dst = ei[N_EDGES + e];
    int et = etype[e];
    int sidx = sign_index(esign[e]);

    #pragma unroll
    for (int half = 0; half < 2; ++half) {
        int o = lane + half * 64;
        int h = o >> 4;
        float sc = scores[e * NH + h];
        float m = dec_f(m_enc[dst * NH + h]);
        float ex = expf(sc - m);
        if ((o & 15) == 0) atomicAdd(Z + dst * NH + h, ex);
        float v = V[src * DIM + o] * rel_v[(et * NH + h) * DKH + (o & 15)];
        float sv = (sidx == 0) ? -1.f : ((sidx == 1) ? 1.f : svn[o]);
        atomicAdd(out + dst * DIM + o, v * sv * ex);
    }
}

// ---------------- pass 3: normalize, skip-mix, LayerNorm ----------------
__global__ __launch_bounds__(128) void k_pass3(
    const float* __restrict__ x, const int* __restrict__ ntype,
    const float* __restrict__ Z, const float* __restrict__ skip,
    const float* __restrict__ gmm, const float* __restrict__ bta,
    float* __restrict__ out)
{
    int n = blockIdx.x;
    int tid = threadIdx.x;
    int t = ntype[n];
    int h = tid >> 4;
    float z = Z[n * NH + h];
    float o = out[n * DIM + tid] / (z + 1e-9f);
    float alpha = 1.f / (1.f + expf(-skip[t]));
    float mix = alpha * o + (1.f - alpha) * x[n * DIM + tid];

    float s = mix, s2 = mix * mix;
    #pragma unroll
    for (int d = 32; d >= 1; d >>= 1) {
        s += __shfl_xor(s, d, 64);
        s2 += __shfl_xor(s2, d, 64);
    }
    __shared__ float ls[2], ls2[2];
    int w = tid >> 6;
    if ((tid & 63) == 0) { ls[w] = s; ls2[w] = s2; }
    __syncthreads();
    float S = ls[0] + ls[1];
    float S2 = ls2[0] + ls2[1];
    float mu = S * (1.f / DIM);
    float var = S2 * (1.f / DIM) - mu * mu;
    float nv = (mix - mu) * rsqrtf(var + 1e-5f);
    out[n * DIM + tid] = nv * gmm[t * DIM + tid] + bta[t * DIM + tid];
}

extern "C" void kernel_launch(void* const* d_in, const int* in_sizes, int n_in,
                              void* d_out, int out_size, void* d_ws, size_t ws_size,
                              hipStream_t stream) {
    const float* x      = (const float*)d_in[0];
    const int*   ntype  = (const int*)d_in[1];
    const int*   ei     = (const int*)d_in[2];
    const int*   etype  = (const int*)d_in[3];
    const int*   esign  = (const int*)d_in[4];
    const float* edist  = (const float*)d_in[5];
    const float* Wq     = (const float*)d_in[6];
    const float* bq     = (const float*)d_in[7];
    const float* Wk     = (const float*)d_in[8];
    const float* bk     = (const float*)d_in[9];
    const float* Wv     = (const float*)d_in[10];
    const float* bv     = (const float*)d_in[11];
    const float* rel_q  = (const float*)d_in[12];
    const float* rel_k  = (const float*)d_in[13];
    const float* rel_v  = (const float*)d_in[14];
    const float* skn    = (const float*)d_in[15];
    const float* svn    = (const float*)d_in[16];
    const float* rbias  = (const float*)d_in[17];
    const float* dalpha = (const float*)d_in[18];
    const float* dtau   = (const float*)d_in[19];
    const float* skip   = (const float*)d_in[20];
    const float* gmm    = (const float*)d_in[21];
    const float* bta    = (const float*)d_in[22];
    float* out = (float*)d_out;

    char* ws = (char*)d_ws;
    float*        Qb     = (float*)(ws + 0);              // N*128 f32 = 25.6 MB
    float*        Kb     = (float*)(ws + 25600000);       // 25.6 MB
    float*        Vb     = (float*)(ws + 51200000);       // 25.6 MB
    float*        scores = (float*)(ws + 76800000);       // E*8 f32 = 25.6 MB
    unsigned int* m_enc  = (unsigned int*)(ws + 102400000); // N*8 u32 = 1.6 MB
    float*        Zb     = (float*)(ws + 104000000);      // N*8 f32 = 1.6 MB
    int*          order  = (int*)(ws + 105600000);        // N i32 = 0.2 MB
    int*          counts = (int*)(ws + 105800000);        // 4 i32
    int*          cursors= counts + 4;                    // 4 i32

    hipMemsetAsync(m_enc, 0, (size_t)N_NODES * NH * 4, stream);   // enc(0) < enc(any finite score)
    hipMemsetAsync(Zb, 0, (size_t)N_NODES * NH * 4, stream);
    hipMemsetAsync(counts, 0, 32, stream);
    hipMemsetAsync(d_out, 0, (size_t)N_NODES * DIM * 4, stream);  // out_un accumulator

    k_count   <<<(N_NODES + 255) / 256, 256, 0, stream>>>(ntype, counts);
    k_offsets <<<1, 1, 0, stream>>>(counts, cursors);
    k_scatter <<<(N_NODES + 255) / 256, 256, 0, stream>>>(ntype, cursors, order);
    k_proj    <<<N_NODES / 8, 128, 0, stream>>>(x, order, ntype, Wq, bq, Wk, bk, Wv, bv, Qb, Kb, Vb);
    k_pass1   <<<(N_EDGES * NH + 255) / 256, 256, 0, stream>>>(Qb, Kb, ei, etype, esign, edist,
                                                               rel_q, rel_k, skn, rbias, dalpha, dtau,
                                                               scores, m_enc);
    k_pass2   <<<N_EDGES / 4, 256, 0, stream>>>(Vb, ei, etype, esign, rel_v, svn,
                                                scores, m_enc, Zb, out);
    k_pass3   <<<N_NODES, 128, 0, stream>>>(x, ntype, Zb, skip, gmm, bta, out);
}

// Round 2
// 900.476 us; speedup vs baseline: 1.4465x; 1.4465x over previous
//
#include <hip/hip_runtime.h>

#define N_NODES 50000
#define N_EDGES 800000
#define DIM 128
#define NT 4
#define NR 6
#define NH 8
#define DKH 16
#define NBLK_SCAN ((N_NODES + 255) / 256)   // 196

__device__ __forceinline__ int sign_index(int s) {
    // es = where((s < -1)|(s==0), -2, clip(s,-1,1)); idx: -1->0, 1->1, else->2
    if (s < -1 || s == 0) return 2;
    return (s == -1) ? 0 : 1;
}

// ---------------- node bucketing by type (for projection) ----------------
__global__ void k_count(const int* __restrict__ ntype, int* __restrict__ counts) {
    int n = blockIdx.x * blockDim.x + threadIdx.x;
    if (n < N_NODES) atomicAdd(&counts[ntype[n]], 1);
}

__global__ void k_offsets(const int* __restrict__ counts, int* __restrict__ cursors) {
    if (blockIdx.x == 0 && threadIdx.x == 0) {
        int acc = 0;
        for (int t = 0; t < NT; ++t) { cursors[t] = acc; acc += counts[t]; }
    }
}

__global__ void k_scatter(const int* __restrict__ ntype, int* __restrict__ cursors,
                          int* __restrict__ order) {
    int n = blockIdx.x * blockDim.x + threadIdx.x;
    if (n < N_NODES) {
        int t = ntype[n];
        int pos = atomicAdd(&cursors[t], 1);
        order[pos] = n;
    }
}

// ---------------- per-type QKV projection ----------------
__global__ __launch_bounds__(128) void k_proj(
    const float* __restrict__ x, const int* __restrict__ order, const int* __restrict__ ntype,
    const float* __restrict__ Wq, const float* __restrict__ bq,
    const float* __restrict__ Wk, const float* __restrict__ bk,
    const float* __restrict__ Wv, const float* __restrict__ bv,
    float* __restrict__ Q, float* __restrict__ K, float* __restrict__ V)
{
    __shared__ float xs[8][DIM];
    __shared__ int nid[8];
    __shared__ int nts[8];
    const int tid = threadIdx.x;
    const int b = blockIdx.x;
    if (tid < 8) {
        int n = order[b * 8 + tid];
        nid[tid] = n;
        nts[tid] = ntype[n];
    }
    __syncthreads();
    #pragma unroll
    for (int j = 0; j < 8; ++j) xs[j][tid] = x[nid[j] * DIM + tid];
    __syncthreads();

    const int o = tid;
    int t0 = nts[0];
    bool uni = true;
    #pragma unroll
    for (int j = 1; j < 8; ++j) uni = uni && (nts[j] == t0);

    if (uni) {
        const float* wq = Wq + t0 * DIM * DIM;
        const float* wk = Wk + t0 * DIM * DIM;
        const float* wv = Wv + t0 * DIM * DIM;
        float aq[8], ak[8], av[8];
        #pragma unroll
        for (int j = 0; j < 8; ++j) { aq[j] = 0.f; ak[j] = 0.f; av[j] = 0.f; }
        for (int i = 0; i < DIM; ++i) {
            float wqv = wq[i * DIM + o];
            float wkv = wk[i * DIM + o];
            float wvv = wv[i * DIM + o];
            #pragma unroll
            for (int j = 0; j < 8; ++j) {
                float xv = xs[j][i];
                aq[j] = fmaf(xv, wqv, aq[j]);
                ak[j] = fmaf(xv, wkv, ak[j]);
                av[j] = fmaf(xv, wvv, av[j]);
            }
        }
        float bqv = bq[t0 * DIM + o], bkv = bk[t0 * DIM + o], bvv = bv[t0 * DIM + o];
        #pragma unroll
        for (int j = 0; j < 8; ++j) {
            int n = nid[j];
            Q[n * DIM + o] = aq[j] + bqv;
            K[n * DIM + o] = ak[j] + bkv;
            V[n * DIM + o] = av[j] + bvv;
        }
    } else {
        for (int j = 0; j < 8; ++j) {
            int t = nts[j];
            float aq = 0.f, ak = 0.f, av = 0.f;
            for (int i = 0; i < DIM; ++i) {
                float xv = xs[j][i];
                aq = fmaf(xv, Wq[(t * DIM + i) * DIM + o], aq);
                ak = fmaf(xv, Wk[(t * DIM + i) * DIM + o], ak);
                av = fmaf(xv, Wv[(t * DIM + i) * DIM + o], av);
            }
            int n = nid[j];
            Q[n * DIM + o] = aq + bq[t * DIM + o];
            K[n * DIM + o] = ak + bk[t * DIM + o];
            V[n * DIM + o] = av + bv[t * DIM + o];
        }
    }
}

// ---------------- edge counting sort by dst ----------------
__global__ void k_hist(const int* __restrict__ ei, int* __restrict__ cnt) {
    int e = blockIdx.x * blockDim.x + threadIdx.x;
    if (e < N_EDGES) atomicAdd(&cnt[ei[N_EDGES + e]], 1);
}

__global__ __launch_bounds__(256) void k_scan1(const int* __restrict__ cnt,
                                               int* __restrict__ offs, int* __restrict__ bsum) {
    __shared__ int s[256];
    int i = blockIdx.x * 256 + threadIdx.x;
    int v = (i < N_NODES) ? cnt[i] : 0;
    s[threadIdx.x] = v;
    __syncthreads();
    for (int d = 1; d < 256; d <<= 1) {
        int add = (threadIdx.x >= d) ? s[threadIdx.x - d] : 0;
        __syncthreads();
        s[threadIdx.x] += add;
        __syncthreads();
    }
    if (i < N_NODES) offs[i] = s[threadIdx.x] - v;   // block-local exclusive
    if (threadIdx.x == 255) bsum[blockIdx.x] = s[255];
}

__global__ __launch_bounds__(256) void k_scan2(const int* __restrict__ bsum,
                                               int* __restrict__ bofs, int* __restrict__ offs) {
    __shared__ int s[256];
    int t = threadIdx.x;
    int v = (t < NBLK_SCAN) ? bsum[t] : 0;
    s[t] = v;
    __syncthreads();
    for (int d = 1; d < 256; d <<= 1) {
        int add = (t >= d) ? s[t - d] : 0;
        __syncthreads();
        s[t] += add;
        __syncthreads();
    }
    if (t < NBLK_SCAN) bofs[t] = s[t] - v;           // exclusive block offsets
    if (t == 0) offs[N_NODES] = N_EDGES;
}

__global__ void k_scan3(int* __restrict__ offs, const int* __restrict__ bofs,
                        int* __restrict__ ecur) {
    int i = blockIdx.x * blockDim.x + threadIdx.x;
    if (i < N_NODES) {
        int off = offs[i] + bofs[i >> 8];
        offs[i] = off;
        ecur[i] = off;
    }
}

__global__ void k_esort(const int* __restrict__ ei, const int* __restrict__ etype,
                        const int* __restrict__ esign, const float* __restrict__ edist,
                        const float* __restrict__ dalpha, const float* __restrict__ dtau,
                        int* __restrict__ ecur,
                        int* __restrict__ src_s, int* __restrict__ meta_s,
                        float* __restrict__ phi_s) {
    int e = blockIdx.x * blockDim.x + threadIdx.x;
    if (e >= N_EDGES) return;
    int dst = ei[N_EDGES + e];
    int pos = atomicAdd(&ecur[dst], 1);
    src_s[pos] = ei[e];
    meta_s[pos] = etype[e] | (sign_index(esign[e]) << 8);
    phi_s[pos] = dalpha[0] * expf(-edist[e] / (dtau[0] + 1e-9f));
}

// ---------------- fused edge attention + aggregation + skip + LN ----------------
// one block (128 threads) per destination node; edges pre-sorted by dst
__global__ __launch_bounds__(128) void k_attn(
    const float* __restrict__ Q, const float* __restrict__ K, const float* __restrict__ V,
    const float* __restrict__ x, const int* __restrict__ ntype,
    const int* __restrict__ offs, const int* __restrict__ src_s,
    const int* __restrict__ meta_s, const float* __restrict__ phi_s,
    const float* __restrict__ rel_q, const float* __restrict__ rel_k,
    const float* __restrict__ rel_v,
    const float* __restrict__ skn, const float* __restrict__ svn,
    const float* __restrict__ rbias, const float* __restrict__ skip,
    const float* __restrict__ gmm, const float* __restrict__ bta,
    float* __restrict__ out)
{
    const int n = blockIdx.x;
    const int o = threadIdx.x;
    const int h = o >> 4;
    const int kk = o & 15;
    const int beg = offs[n], end = offs[n + 1];

    const float q = Q[n * DIM + o];
    const float sknv = skn[o], svnv = svn[o];

    float m = -1e30f, Z = 0.f, acc = 0.f;
    for (int j = beg; j < end; ++j) {
        int src = src_s[j];
        int meta = meta_s[j];
        int et = meta & 0xff;
        int sidx = meta >> 8;
        float kv = K[src * DIM + o];
        float vv = V[src * DIM + o];
        int rb = (et * NH + h) * DKH + kk;
        float ke = kv * rel_k[rb];
        if (sidx == 2) ke *= sknv;
        float p = q * rel_q[rb] * ke;
        // reduce over the 16 lanes of this head
        p += __shfl_xor(p, 1, 16);
        p += __shfl_xor(p, 2, 16);
        p += __shfl_xor(p, 4, 16);
        p += __shfl_xor(p, 8, 16);
        float dot = (sidx == 0) ? -p : p;
        float sc = dot * 0.25f + rbias[et * NH + h] + phi_s[j];

        float nm = fmaxf(m, sc);
        float scale = expf(m - nm);
        float ex = expf(sc - nm);
        float sv = (sidx == 0) ? -1.f : (sidx == 1 ? 1.f : svnv);
        Z = Z * scale + ex;
        acc = acc * scale + vv * rel_v[rb] * sv * ex;
        m = nm;
    }

    float oo = acc / (Z + 1e-9f);
    int t = ntype[n];
    float alpha = 1.f / (1.f + expf(-skip[t]));
    float mix = alpha * oo + (1.f - alpha) * x[n * DIM + o];

    float s = mix, s2 = mix * mix;
    #pragma unroll
    for (int d = 32; d >= 1; d >>= 1) {
        s += __shfl_xor(s, d, 64);
        s2 += __shfl_xor(s2, d, 64);
    }
    __shared__ float ls[2], ls2[2];
    int w = o >> 6;
    if ((o & 63) == 0) { ls[w] = s; ls2[w] = s2; }
    __syncthreads();
    float S = ls[0] + ls[1];
    float S2 = ls2[0] + ls2[1];
    float mu = S * (1.f / DIM);
    float var = S2 * (1.f / DIM) - mu * mu;
    float nv = (mix - mu) * rsqrtf(var + 1e-5f);
    out[n * DIM + o] = nv * gmm[t * DIM + o] + bta[t * DIM + o];
}

extern "C" void kernel_launch(void* const* d_in, const int* in_sizes, int n_in,
                              void* d_out, int out_size, void* d_ws, size_t ws_size,
                              hipStream_t stream) {
    const float* x      = (const float*)d_in[0];
    const int*   ntype  = (const int*)d_in[1];
    const int*   ei     = (const int*)d_in[2];
    const int*   etype  = (const int*)d_in[3];
    const int*   esign  = (const int*)d_in[4];
    const float* edist  = (const float*)d_in[5];
    const float* Wq     = (const float*)d_in[6];
    const float* bq     = (const float*)d_in[7];
    const float* Wk     = (const float*)d_in[8];
    const float* bk     = (const float*)d_in[9];
    const float* Wv     = (const float*)d_in[10];
    const float* bv     = (const float*)d_in[11];
    const float* rel_q  = (const float*)d_in[12];
    const float* rel_k  = (const float*)d_in[13];
    const float* rel_v  = (const float*)d_in[14];
    const float* skn    = (const float*)d_in[15];
    const float* svn    = (const float*)d_in[16];
    const float* rbias  = (const float*)d_in[17];
    const float* dalpha = (const float*)d_in[18];
    const float* dtau   = (const float*)d_in[19];
    const float* skip   = (const float*)d_in[20];
    const float* gmm    = (const float*)d_in[21];
    const float* bta    = (const float*)d_in[22];
    float* out = (float*)d_out;

    char* ws = (char*)d_ws;
    float* Qb     = (float*)(ws + 0);            // 25.6 MB
    float* Kb     = (float*)(ws + 25600000);     // 25.6 MB
    float* Vb     = (float*)(ws + 51200000);     // 25.6 MB
    int*   cnt    = (int*)  (ws + 76800000);     // N i32
    int*   offs   = (int*)  (ws + 77100000);     // N+1 i32
    int*   ecur   = (int*)  (ws + 77400000);     // N i32
    int*   bsum   = (int*)  (ws + 77700000);     // 256 i32
    int*   bofs   = (int*)  (ws + 77702000);     // 256 i32
    int*   src_s  = (int*)  (ws + 78000000);     // E i32
    int*   meta_s = (int*)  (ws + 81200000);     // E i32
    float* phi_s  = (float*)(ws + 84400000);     // E f32
    int*   order  = (int*)  (ws + 87600000);     // N i32
    int*   counts = (int*)  (ws + 87900000);     // 4 i32
    int*   cursors= counts + 4;                  // 4 i32

    hipMemsetAsync(cnt, 0, (size_t)N_NODES * 4, stream);
    hipMemsetAsync(counts, 0, 32, stream);

    // node bucketing + projection
    k_count   <<<(N_NODES + 255) / 256, 256, 0, stream>>>(ntype, counts);
    k_offsets <<<1, 1, 0, stream>>>(counts, cursors);
    k_scatter <<<(N_NODES + 255) / 256, 256, 0, stream>>>(ntype, cursors, order);
    k_proj    <<<N_NODES / 8, 128, 0, stream>>>(x, order, ntype, Wq, bq, Wk, bk, Wv, bv, Qb, Kb, Vb);

    // edge counting-sort by destination
    k_hist  <<<(N_EDGES + 255) / 256, 256, 0, stream>>>(ei, cnt);
    k_scan1 <<<NBLK_SCAN, 256, 0, stream>>>(cnt, offs, bsum);
    k_scan2 <<<1, 256, 0, stream>>>(bsum, bofs, offs);
    k_scan3 <<<NBLK_SCAN, 256, 0, stream>>>(offs, bofs, ecur);
    k_esort <<<(N_EDGES + 255) / 256, 256, 0, stream>>>(ei, etype, esign, edist, dalpha, dtau,
                                                        ecur, src_s, meta_s, phi_s);

    // fused attention + aggregation + skip + LayerNorm
    k_attn <<<N_NODES, 128, 0, stream>>>(Qb, Kb, Vb, x, ntype, offs, src_s, meta_s, phi_s,
                                         rel_q, rel_k, rel_v, skn, svn, rbias, skip,
                                         gmm, bta, out);
}

// Round 3
// 374.838 us; speedup vs baseline: 3.4750x; 2.4023x over previous
//
#include <hip/hip_runtime.h>

#define N_NODES 50000
#define N_EDGES 800000
#define DIM 128
#define NT 4
#define NR 6
#define NH 8
#define DKH 16
#define NBLK_SCAN ((N_NODES + 255) / 256)   // 196

__device__ __forceinline__ int sign_index(int s) {
    // es = where((s < -1)|(s==0), -2, clip(s,-1,1)); idx: -1->0, 1->1, else->2
    if (s < -1 || s == 0) return 2;
    return (s == -1) ? 0 : 1;
}

// ---------------- node bucketing by type (contention-free) ----------------
// step 1: per-block histogram of node types
__global__ __launch_bounds__(256) void k_typehist(const int* __restrict__ ntype,
                                                  int* __restrict__ bhist) {
    __shared__ int h[NT];
    if (threadIdx.x < NT) h[threadIdx.x] = 0;
    __syncthreads();
    int n = blockIdx.x * 256 + threadIdx.x;
    if (n < N_NODES) atomicAdd(&h[ntype[n]], 1);
    __syncthreads();
    if (threadIdx.x < NT) bhist[blockIdx.x * NT + threadIdx.x] = h[threadIdx.x];
}

// step 2: exclusive scan over (type-major) block histograms -> per-(block,type) base
__global__ void k_typescan(const int* __restrict__ bhist, int* __restrict__ bbase) {
    if (threadIdx.x == 0 && blockIdx.x == 0) {
        int acc = 0;
        for (int t = 0; t < NT; ++t)
            for (int b = 0; b < NBLK_SCAN; ++b) {
                bbase[b * NT + t] = acc;
                acc += bhist[b * NT + t];
            }
    }
}

// step 3: scatter using per-block LDS cursors (no global atomics)
__global__ __launch_bounds__(256) void k_scatter2(const int* __restrict__ ntype,
                                                  const int* __restrict__ bbase,
                                                  int* __restrict__ order) {
    __shared__ int cur[NT];
    if (threadIdx.x < NT) cur[threadIdx.x] = bbase[blockIdx.x * NT + threadIdx.x];
    __syncthreads();
    int n = blockIdx.x * 256 + threadIdx.x;
    if (n < N_NODES) {
        int t = ntype[n];
        int pos = atomicAdd(&cur[t], 1);   // LDS atomic: cheap
        order[pos] = n;
    }
}

// ---------------- per-type QKV projection ----------------
__global__ __launch_bounds__(128) void k_proj(
    const float* __restrict__ x, const int* __restrict__ order, const int* __restrict__ ntype,
    const float* __restrict__ Wq, const float* __restrict__ bq,
    const float* __restrict__ Wk, const float* __restrict__ bk,
    const float* __restrict__ Wv, const float* __restrict__ bv,
    float* __restrict__ Q, float* __restrict__ K, float* __restrict__ V)
{
    __shared__ float xs[8][DIM];
    __shared__ int nid[8];
    __shared__ int nts[8];
    const int tid = threadIdx.x;
    const int b = blockIdx.x;
    if (tid < 8) {
        int n = order[b * 8 + tid];
        nid[tid] = n;
        nts[tid] = ntype[n];
    }
    __syncthreads();
    #pragma unroll
    for (int j = 0; j < 8; ++j) xs[j][tid] = x[nid[j] * DIM + tid];
    __syncthreads();

    const int o = tid;
    int t0 = nts[0];
    bool uni = true;
    #pragma unroll
    for (int j = 1; j < 8; ++j) uni = uni && (nts[j] == t0);

    if (uni) {
        const float* wq = Wq + t0 * DIM * DIM;
        const float* wk = Wk + t0 * DIM * DIM;
        const float* wv = Wv + t0 * DIM * DIM;
        float aq[8], ak[8], av[8];
        #pragma unroll
        for (int j = 0; j < 8; ++j) { aq[j] = 0.f; ak[j] = 0.f; av[j] = 0.f; }
        for (int i = 0; i < DIM; ++i) {
            float wqv = wq[i * DIM + o];
            float wkv = wk[i * DIM + o];
            float wvv = wv[i * DIM + o];
            #pragma unroll
            for (int j = 0; j < 8; ++j) {
                float xv = xs[j][i];
                aq[j] = fmaf(xv, wqv, aq[j]);
                ak[j] = fmaf(xv, wkv, ak[j]);
                av[j] = fmaf(xv, wvv, av[j]);
            }
        }
        float bqv = bq[t0 * DIM + o], bkv = bk[t0 * DIM + o], bvv = bv[t0 * DIM + o];
        #pragma unroll
        for (int j = 0; j < 8; ++j) {
            int n = nid[j];
            Q[n * DIM + o] = aq[j] + bqv;
            K[n * DIM + o] = ak[j] + bkv;
            V[n * DIM + o] = av[j] + bvv;
        }
    } else {
        for (int j = 0; j < 8; ++j) {
            int t = nts[j];
            float aq = 0.f, ak = 0.f, av = 0.f;
            for (int i = 0; i < DIM; ++i) {
                float xv = xs[j][i];
                aq = fmaf(xv, Wq[(t * DIM + i) * DIM + o], aq);
                ak = fmaf(xv, Wk[(t * DIM + i) * DIM + o], ak);
                av = fmaf(xv, Wv[(t * DIM + i) * DIM + o], av);
            }
            int n = nid[j];
            Q[n * DIM + o] = aq + bq[t * DIM + o];
            K[n * DIM + o] = ak + bk[t * DIM + o];
            V[n * DIM + o] = av + bv[t * DIM + o];
        }
    }
}

// ---------------- edge counting sort by dst ----------------
__global__ void k_hist(const int* __restrict__ ei, int* __restrict__ cnt) {
    int e = blockIdx.x * blockDim.x + threadIdx.x;
    if (e < N_EDGES) atomicAdd(&cnt[ei[N_EDGES + e]], 1);
}

__global__ __launch_bounds__(256) void k_scan1(const int* __restrict__ cnt,
                                               int* __restrict__ offs, int* __restrict__ bsum) {
    __shared__ int s[256];
    int i = blockIdx.x * 256 + threadIdx.x;
    int v = (i < N_NODES) ? cnt[i] : 0;
    s[threadIdx.x] = v;
    __syncthreads();
    for (int d = 1; d < 256; d <<= 1) {
        int add = (threadIdx.x >= d) ? s[threadIdx.x - d] : 0;
        __syncthreads();
        s[threadIdx.x] += add;
        __syncthreads();
    }
    if (i < N_NODES) offs[i] = s[threadIdx.x] - v;   // block-local exclusive
    if (threadIdx.x == 255) bsum[blockIdx.x] = s[255];
}

__global__ __launch_bounds__(256) void k_scan2(const int* __restrict__ bsum,
                                               int* __restrict__ bofs, int* __restrict__ offs) {
    __shared__ int s[256];
    int t = threadIdx.x;
    int v = (t < NBLK_SCAN) ? bsum[t] : 0;
    s[t] = v;
    __syncthreads();
    for (int d = 1; d < 256; d <<= 1) {
        int add = (t >= d) ? s[t - d] : 0;
        __syncthreads();
        s[t] += add;
        __syncthreads();
    }
    if (t < NBLK_SCAN) bofs[t] = s[t] - v;           // exclusive block offsets
    if (t == 0) offs[N_NODES] = N_EDGES;
}

__global__ void k_scan3(int* __restrict__ offs, const int* __restrict__ bofs,
                        int* __restrict__ ecur) {
    int i = blockIdx.x * blockDim.x + threadIdx.x;
    if (i < N_NODES) {
        int off = offs[i] + bofs[i >> 8];
        offs[i] = off;
        ecur[i] = off;
    }
}

__global__ void k_esort(const int* __restrict__ ei, const int* __restrict__ etype,
                        const int* __restrict__ esign, const float* __restrict__ edist,
                        const float* __restrict__ dalpha, const float* __restrict__ dtau,
                        int* __restrict__ ecur,
                        int* __restrict__ src_s, int* __restrict__ meta_s,
                        float* __restrict__ phi_s) {
    int e = blockIdx.x * blockDim.x + threadIdx.x;
    if (e >= N_EDGES) return;
    int dst = ei[N_EDGES + e];
    int pos = atomicAdd(&ecur[dst], 1);
    src_s[pos] = ei[e];
    meta_s[pos] = etype[e] | (sign_index(esign[e]) << 8);
    phi_s[pos] = dalpha[0] * expf(-edist[e] / (dtau[0] + 1e-9f));
}

// ---------------- fused edge attention + aggregation + skip + LN ----------------
// one block (128 threads) per destination node; edges pre-sorted by dst
__global__ __launch_bounds__(128) void k_attn(
    const float* __restrict__ Q, const float* __restrict__ K, const float* __restrict__ V,
    const float* __restrict__ x, const int* __restrict__ ntype,
    const int* __restrict__ offs, const int* __restrict__ src_s,
    const int* __restrict__ meta_s, const float* __restrict__ phi_s,
    const float* __restrict__ rel_q, const float* __restrict__ rel_k,
    const float* __restrict__ rel_v,
    const float* __restrict__ skn, const float* __restrict__ svn,
    const float* __restrict__ rbias, const float* __restrict__ skip,
    const float* __restrict__ gmm, const float* __restrict__ bta,
    float* __restrict__ out)
{
    const int n = blockIdx.x;
    const int o = threadIdx.x;
    const int h = o >> 4;
    const int kk = o & 15;
    const int beg = offs[n], end = offs[n + 1];

    const float q = Q[n * DIM + o];
    const float sknv = skn[o], svnv = svn[o];

    float m = -1e30f, Z = 0.f, acc = 0.f;
    for (int j = beg; j < end; ++j) {
        int src = src_s[j];
        int meta = meta_s[j];
        int et = meta & 0xff;
        int sidx = meta >> 8;
        float kv = K[src * DIM + o];
        float vv = V[src * DIM + o];
        int rb = (et * NH + h) * DKH + kk;
        float ke = kv * rel_k[rb];
        if (sidx == 2) ke *= sknv;
        float p = q * rel_q[rb] * ke;
        // reduce over the 16 lanes of this head
        p += __shfl_xor(p, 1, 16);
        p += __shfl_xor(p, 2, 16);
        p += __shfl_xor(p, 4, 16);
        p += __shfl_xor(p, 8, 16);
        float dot = (sidx == 0) ? -p : p;
        float sc = dot * 0.25f + rbias[et * NH + h] + phi_s[j];

        float nm = fmaxf(m, sc);
        float scale = expf(m - nm);
        float ex = expf(sc - nm);
        float sv = (sidx == 0) ? -1.f : (sidx == 1 ? 1.f : svnv);
        Z = Z * scale + ex;
        acc = acc * scale + vv * rel_v[rb] * sv * ex;
        m = nm;
    }

    float oo = acc / (Z + 1e-9f);
    int t = ntype[n];
    float alpha = 1.f / (1.f + expf(-skip[t]));
    float mix = alpha * oo + (1.f - alpha) * x[n * DIM + o];

    float s = mix, s2 = mix * mix;
    #pragma unroll
    for (int d = 32; d >= 1; d >>= 1) {
        s += __shfl_xor(s, d, 64);
        s2 += __shfl_xor(s2, d, 64);
    }
    __shared__ float ls[2], ls2[2];
    int w = o >> 6;
    if ((o & 63) == 0) { ls[w] = s; ls2[w] = s2; }
    __syncthreads();
    float S = ls[0] + ls[1];
    float S2 = ls2[0] + ls2[1];
    float mu = S * (1.f / DIM);
    float var = S2 * (1.f / DIM) - mu * mu;
    float nv = (mix - mu) * rsqrtf(var + 1e-5f);
    out[n * DIM + o] = nv * gmm[t * DIM + o] + bta[t * DIM + o];
}

extern "C" void kernel_launch(void* const* d_in, const int* in_sizes, int n_in,
                              void* d_out, int out_size, void* d_ws, size_t ws_size,
                              hipStream_t stream) {
    const float* x      = (const float*)d_in[0];
    const int*   ntype  = (const int*)d_in[1];
    const int*   ei     = (const int*)d_in[2];
    const int*   etype  = (const int*)d_in[3];
    const int*   esign  = (const int*)d_in[4];
    const float* edist  = (const float*)d_in[5];
    const float* Wq     = (const float*)d_in[6];
    const float* bq     = (const float*)d_in[7];
    const float* Wk     = (const float*)d_in[8];
    const float* bk     = (const float*)d_in[9];
    const float* Wv     = (const float*)d_in[10];
    const float* bv     = (const float*)d_in[11];
    const float* rel_q  = (const float*)d_in[12];
    const float* rel_k  = (const float*)d_in[13];
    const float* rel_v  = (const float*)d_in[14];
    const float* skn    = (const float*)d_in[15];
    const float* svn    = (const float*)d_in[16];
    const float* rbias  = (const float*)d_in[17];
    const float* dalpha = (const float*)d_in[18];
    const float* dtau   = (const float*)d_in[19];
    const float* skip   = (const float*)d_in[20];
    const float* gmm    = (const float*)d_in[21];
    const float* bta    = (const float*)d_in[22];
    float* out = (float*)d_out;

    char* ws = (char*)d_ws;
    float* Qb     = (float*)(ws + 0);            // 25.6 MB
    float* Kb     = (float*)(ws + 25600000);     // 25.6 MB
    float* Vb     = (float*)(ws + 51200000);     // 25.6 MB
    int*   cnt    = (int*)  (ws + 76800000);     // N i32
    int*   offs   = (int*)  (ws + 77100000);     // N+1 i32
    int*   ecur   = (int*)  (ws + 77400000);     // N i32
    int*   bsum   = (int*)  (ws + 77700000);     // 256 i32
    int*   bofs   = (int*)  (ws + 77702000);     // 256 i32
    int*   src_s  = (int*)  (ws + 78000000);     // E i32
    int*   meta_s = (int*)  (ws + 81200000);     // E i32
    float* phi_s  = (float*)(ws + 84400000);     // E f32
    int*   order  = (int*)  (ws + 87600000);     // N i32
    int*   bhist  = (int*)  (ws + 87900000);     // 196*4 i32
    int*   bbase  = (int*)  (ws + 87910000);     // 196*4 i32

    hipMemsetAsync(cnt, 0, (size_t)N_NODES * 4, stream);

    // node bucketing by type (contention-free) + projection
    k_typehist <<<NBLK_SCAN, 256, 0, stream>>>(ntype, bhist);
    k_typescan <<<1, 1, 0, stream>>>(bhist, bbase);
    k_scatter2 <<<NBLK_SCAN, 256, 0, stream>>>(ntype, bbase, order);
    k_proj     <<<N_NODES / 8, 128, 0, stream>>>(x, order, ntype, Wq, bq, Wk, bk, Wv, bv, Qb, Kb, Vb);

    // edge counting-sort by destination
    k_hist  <<<(N_EDGES + 255) / 256, 256, 0, stream>>>(ei, cnt);
    k_scan1 <<<NBLK_SCAN, 256, 0, stream>>>(cnt, offs, bsum);
    k_scan2 <<<1, 256, 0, stream>>>(bsum, bofs, offs);
    k_scan3 <<<NBLK_SCAN, 256, 0, stream>>>(offs, bofs, ecur);
    k_esort <<<(N_EDGES + 255) / 256, 256, 0, stream>>>(ei, etype, esign, edist, dalpha, dtau,
                                                        ecur, src_s, meta_s, phi_s);

    // fused attention + aggregation + skip + LayerNorm
    k_attn <<<N_NODES, 128, 0, stream>>>(Qb, Kb, Vb, x, ntype, offs, src_s, meta_s, phi_s,
                                         rel_q, rel_k, rel_v, skn, svn, rbias, skip,
                                         gmm, bta, out);
}

// Round 4
// 312.480 us; speedup vs baseline: 4.1685x; 1.1996x over previous
//
#include <hip/hip_runtime.h>

#define N_NODES 50000
#define N_EDGES 800000
#define DIM 128
#define NT 4
#define NR 6
#define NH 8
#define DKH 16
#define NBLK_SCAN ((N_NODES + 255) / 256)   // 196
#define NTILE_ROW 3129                      // ceil((N + 4*15)/16)
#define NPAD_MAX (NTILE_ROW * 16)           // 50064

typedef __attribute__((ext_vector_type(8))) short bf16x8;
typedef __attribute__((ext_vector_type(4))) float f32x4;

__device__ __forceinline__ unsigned short f2bf(float f) {
    unsigned int u = __float_as_uint(f);
    return (unsigned short)((u + 0x7fffu + ((u >> 16) & 1u)) >> 16);
}

__device__ __forceinline__ int sign_index(int s) {
    // es = where((s < -1)|(s==0), -2, clip(s,-1,1)); idx: -1->0, 1->1, else->2
    if (s < -1 || s == 0) return 2;
    return (s == -1) ? 0 : 1;
}

// ---------------- node bucketing by type (contention-free, padded to x16) ----------------
__global__ __launch_bounds__(256) void k_typehist(const int* __restrict__ ntype,
                                                  int* __restrict__ bhist) {
    __shared__ int h[NT];
    if (threadIdx.x < NT) h[threadIdx.x] = 0;
    __syncthreads();
    int n = blockIdx.x * 256 + threadIdx.x;
    if (n < N_NODES) atomicAdd(&h[ntype[n]], 1);
    __syncthreads();
    if (threadIdx.x < NT) bhist[blockIdx.x * NT + threadIdx.x] = h[threadIdx.x];
}

// scan block histograms (type-major) -> per-(block,type) bases with x16-padded type bases
__global__ __launch_bounds__(1024) void k_typescan(const int* __restrict__ bhist,
                                                   int* __restrict__ bbase,
                                                   int* __restrict__ pb_g) {
    __shared__ int s[1024];
    __shared__ int pb[NT + 1];
    int tid = threadIdx.x;
    int t = tid / NBLK_SCAN;
    int b = tid - t * NBLK_SCAN;
    int v = (tid < NT * NBLK_SCAN) ? bhist[b * NT + t] : 0;
    s[tid] = v;
    __syncthreads();
    for (int d = 1; d < 1024; d <<= 1) {
        int add = (tid >= d) ? s[tid - d] : 0;
        __syncthreads();
        s[tid] += add;
        __syncthreads();
    }
    if (tid == 0) {
        int acc = 0;
        for (int tt = 0; tt < NT; ++tt) {
            pb[tt] = acc;
            int tot = s[(tt + 1) * NBLK_SCAN - 1] - (tt ? s[tt * NBLK_SCAN - 1] : 0);
            acc += ((tot + 15) >> 4) << 4;
        }
        pb[NT] = acc;
    }
    __syncthreads();
    if (tid < NT * NBLK_SCAN) {
        int excl = s[tid] - v;
        int base_t = t ? s[t * NBLK_SCAN - 1] : 0;
        bbase[b * NT + t] = pb[t] + (excl - base_t);
    }
    if (tid <= NT) pb_g[tid] = pb[tid];
}

__global__ __launch_bounds__(256) void k_scatter2(const int* __restrict__ ntype,
                                                  const int* __restrict__ bbase,
                                                  int* __restrict__ order_pad) {
    __shared__ int cur[NT];
    if (threadIdx.x < NT) cur[threadIdx.x] = bbase[blockIdx.x * NT + threadIdx.x];
    __syncthreads();
    int n = blockIdx.x * 256 + threadIdx.x;
    if (n < N_NODES) {
        int t = ntype[n];
        int pos = atomicAdd(&cur[t], 1);   // LDS atomic
        order_pad[pos] = n;
    }
}

// ---------------- prep: x -> bf16, W -> bf16 transposed, weight tables ----------------
__global__ __launch_bounds__(256) void k_xcvt(const float* __restrict__ x,
                                              unsigned short* __restrict__ xb) {
    int i = blockIdx.x * 256 + threadIdx.x;   // per float4
    if (i >= N_NODES * DIM / 4) return;
    float4 v = ((const float4*)x)[i];
    ushort4 o;
    o.x = f2bf(v.x); o.y = f2bf(v.y); o.z = f2bf(v.z); o.w = f2bf(v.w);
    ((ushort4*)xb)[i] = o;
}

// Wt layout: [(t*3+sel)][out][in] bf16
__global__ __launch_bounds__(128) void k_wt(const float* __restrict__ Wq,
                                            const float* __restrict__ Wk,
                                            const float* __restrict__ Wv,
                                            unsigned short* __restrict__ Wt) {
    int blk = blockIdx.x;                 // (t*3+sel)*128 + out
    int out = blk & 127;
    int ts = blk >> 7;
    int sel = ts % 3, t = ts / 3;
    const float* W = sel == 0 ? Wq : (sel == 1 ? Wk : Wv);
    int in = threadIdx.x;
    float v = W[((size_t)t * DIM + in) * DIM + out];
    Wt[(size_t)blk * DIM + in] = f2bf(v);
}

// wqk[cmb][o] = rel_q*rel_k*sign_k*0.25 ; wv[cmb][o] = rel_v*sign_v ; cmb = sidx*8+et
__global__ void k_tbl(const float* __restrict__ rel_q, const float* __restrict__ rel_k,
                      const float* __restrict__ rel_v,
                      const float* __restrict__ skn, const float* __restrict__ svn,
                      float* __restrict__ wqk, float* __restrict__ wv) {
    int i = blockIdx.x * 256 + threadIdx.x;
    if (i >= 3 * NR * DIM) return;
    int o = i & 127;
    int c = i >> 7;
    int et = c % NR, sidx = c / NR;
    int h = o >> 4, kk = o & 15;
    int rbi = (et * NH + h) * DKH + kk;
    float sgk = sidx == 0 ? -1.f : (sidx == 1 ? 1.f : skn[o]);
    float sgv = sidx == 0 ? -1.f : (sidx == 1 ? 1.f : svn[o]);
    int cmb = sidx * 8 + et;
    wqk[cmb * DIM + o] = rel_q[rbi] * rel_k[rbi] * sgk * 0.25f;
    wv[cmb * DIM + o]  = rel_v[rbi] * sgv;
}

// ---------------- MFMA projection: Q (f32), K/V (bf16) ----------------
__global__ __launch_bounds__(256) void k_projm(
    const unsigned short* __restrict__ xb, const unsigned short* __restrict__ Wt,
    const int* __restrict__ order_pad, const int* __restrict__ pb_g,
    const float* __restrict__ bq, const float* __restrict__ bk, const float* __restrict__ bv,
    float* __restrict__ Qf, unsigned short* __restrict__ K16, unsigned short* __restrict__ V16)
{
    int row0 = blockIdx.x * 16;
    if (row0 >= pb_g[NT]) return;
    int t = (row0 >= pb_g[3]) ? 3 : (row0 >= pb_g[2]) ? 2 : (row0 >= pb_g[1]) ? 1 : 0;
    int wave = threadIdx.x >> 6, lane = threadIdx.x & 63;
    int ocol = blockIdx.y * 64 + wave * 16 + (lane & 15);
    int sel = ocol >> 7, wcol = ocol & 127;
    int arow = row0 + (lane & 15);
    int nidA = order_pad[arow];
    const unsigned short* xrow = xb + (size_t)(nidA < 0 ? 0 : nidA) * DIM;
    const unsigned short* wrow = Wt + ((size_t)(t * 3 + sel) * DIM + wcol) * DIM;
    int ko = (lane >> 4) * 8;
    f32x4 acc = {0.f, 0.f, 0.f, 0.f};
    #pragma unroll
    for (int kt = 0; kt < 4; ++kt) {
        bf16x8 a = *(const bf16x8*)(xrow + kt * 32 + ko);
        bf16x8 b = *(const bf16x8*)(wrow + kt * 32 + ko);
        acc = __builtin_amdgcn_mfma_f32_16x16x32_bf16(a, b, acc, 0, 0, 0);
    }
    const float* bias_p = sel == 0 ? bq : (sel == 1 ? bk : bv);
    float bias = bias_p[t * DIM + wcol];
    #pragma unroll
    for (int r = 0; r < 4; ++r) {
        int drow = row0 + (lane >> 4) * 4 + r;
        int nid = order_pad[drow];
        if (nid < 0) continue;
        float v = acc[r] + bias;
        if (sel == 0)      Qf [(size_t)nid * DIM + wcol] = v;
        else if (sel == 1) K16[(size_t)nid * DIM + wcol] = f2bf(v);
        else               V16[(size_t)nid * DIM + wcol] = f2bf(v);
    }
}

// ---------------- edge counting sort by dst ----------------
__global__ void k_hist(const int* __restrict__ ei, int* __restrict__ cnt) {
    int e = blockIdx.x * blockDim.x + threadIdx.x;
    if (e < N_EDGES) atomicAdd(&cnt[ei[N_EDGES + e]], 1);
}

__global__ __launch_bounds__(256) void k_scan1(const int* __restrict__ cnt,
                                               int* __restrict__ offs, int* __restrict__ bsum) {
    __shared__ int s[256];
    int i = blockIdx.x * 256 + threadIdx.x;
    int v = (i < N_NODES) ? cnt[i] : 0;
    s[threadIdx.x] = v;
    __syncthreads();
    for (int d = 1; d < 256; d <<= 1) {
        int add = (threadIdx.x >= d) ? s[threadIdx.x - d] : 0;
        __syncthreads();
        s[threadIdx.x] += add;
        __syncthreads();
    }
    if (i < N_NODES) offs[i] = s[threadIdx.x] - v;
    if (threadIdx.x == 255) bsum[blockIdx.x] = s[255];
}

__global__ __launch_bounds__(256) void k_scan2(const int* __restrict__ bsum,
                                               int* __restrict__ bofs, int* __restrict__ offs) {
    __shared__ int s[256];
    int t = threadIdx.x;
    int v = (t < NBLK_SCAN) ? bsum[t] : 0;
    s[t] = v;
    __syncthreads();
    for (int d = 1; d < 256; d <<= 1) {
        int add = (t >= d) ? s[t - d] : 0;
        __syncthreads();
        s[t] += add;
        __syncthreads();
    }
    if (t < NBLK_SCAN) bofs[t] = s[t] - v;
    if (t == 0) offs[N_NODES] = N_EDGES;
}

__global__ void k_scan3(int* __restrict__ offs, const int* __restrict__ bofs,
                        int* __restrict__ ecur) {
    int i = blockIdx.x * blockDim.x + threadIdx.x;
    if (i < N_NODES) {
        int off = offs[i] + bofs[i >> 8];
        offs[i] = off;
        ecur[i] = off;
    }
}

__global__ void k_esort(const int* __restrict__ ei, const int* __restrict__ etype,
                        const int* __restrict__ esign, const float* __restrict__ edist,
                        const float* __restrict__ dalpha, const float* __restrict__ dtau,
                        int* __restrict__ ecur,
                        int* __restrict__ packed_s, float* __restrict__ phi_s) {
    int e = blockIdx.x * blockDim.x + threadIdx.x;
    if (e >= N_EDGES) return;
    int dst = ei[N_EDGES + e];
    int pos = atomicAdd(&ecur[dst], 1);
    int cmb = sign_index(esign[e]) * 8 + etype[e];
    packed_s[pos] = ei[e] | (cmb << 16);
    phi_s[pos] = dalpha[0] * __expf(-edist[e] / (dtau[0] + 1e-9f));
}

// ---------------- fused attention + aggregation + skip + LN ----------------
// block = 128 threads = 2 waves; each wave owns alternating edges; lane = element pair
__global__ __launch_bounds__(128) void k_attn(
    const float* __restrict__ Qf, const unsigned int* __restrict__ K16u,
    const unsigned int* __restrict__ V16u,
    const float* __restrict__ x, const int* __restrict__ ntype,
    const int* __restrict__ offs, const int* __restrict__ packed_s,
    const float* __restrict__ phi_s,
    const float* __restrict__ wqk, const float* __restrict__ wv,
    const float* __restrict__ rbias, const float* __restrict__ skip,
    const float* __restrict__ gmm, const float* __restrict__ bta,
    float* __restrict__ out)
{
    const int n = blockIdx.x;
    const int tid = threadIdx.x;
    const int wave = tid >> 6, lane = tid & 63;
    const int h = lane >> 3;
    const int beg = offs[n], end = offs[n + 1];

    const float2 q2 = ((const float2*)(Qf + (size_t)n * DIM))[lane];

    // scores are bounded (|dot/4| ~ few, phi <= alpha): exp without max-shift is safe in f32,
    // and softmax is shift-invariant -> identical result, shorter dependency chain.
    float Z = 0.f, a0 = 0.f, a1 = 0.f;
    for (int j = beg + wave; j < end; j += 2) {
        int pk = packed_s[j];
        float phi = phi_s[j];
        int src = pk & 0xffff;
        int cmb = pk >> 16;
        unsigned int ku = K16u[src * 64 + lane];
        float2 w = ((const float2*)(wqk + cmb * DIM))[lane];
        float k0 = __uint_as_float(ku << 16);
        float k1 = __uint_as_float(ku & 0xffff0000u);
        float p = (q2.x * w.x) * k0 + (q2.y * w.y) * k1;
        p += __shfl_xor(p, 1, 8);
        p += __shfl_xor(p, 2, 8);
        p += __shfl_xor(p, 4, 8);
        float sc = p + rbias[(cmb & 7) * NH + h] + phi;
        float ex = __expf(sc);
        unsigned int vu = V16u[src * 64 + lane];
        float2 w2 = ((const float2*)(wv + cmb * DIM))[lane];
        float v0 = __uint_as_float(vu << 16) * w2.x;
        float v1 = __uint_as_float(vu & 0xffff0000u) * w2.y;
        Z += ex;
        a0 = fmaf(v0, ex, a0);
        a1 = fmaf(v1, ex, a1);
    }

    __shared__ float sZ[2][64], s0[2][64], s1[2][64];
    sZ[wave][lane] = Z; s0[wave][lane] = a0; s1[wave][lane] = a1;
    __syncthreads();
    int pl = tid >> 1;
    float Zc = sZ[0][pl] + sZ[1][pl];
    float av = (tid & 1) ? (s1[0][pl] + s1[1][pl]) : (s0[0][pl] + s0[1][pl]);
    float oo = av / (Zc + 1e-9f);

    int t = ntype[n];
    float alpha = 1.f / (1.f + __expf(-skip[t]));
    float mix = alpha * oo + (1.f - alpha) * x[(size_t)n * DIM + tid];

    float s = mix, s2 = mix * mix;
    #pragma unroll
    for (int d = 32; d >= 1; d >>= 1) {
        s += __shfl_xor(s, d, 64);
        s2 += __shfl_xor(s2, d, 64);
    }
    __shared__ float ls[2], ls2[2];
    int w = tid >> 6;
    if ((tid & 63) == 0) { ls[w] = s; ls2[w] = s2; }
    __syncthreads();
    float S = ls[0] + ls[1];
    float S2 = ls2[0] + ls2[1];
    float mu = S * (1.f / DIM);
    float var = S2 * (1.f / DIM) - mu * mu;
    float nv = (mix - mu) * rsqrtf(var + 1e-5f);
    out[(size_t)n * DIM + tid] = nv * gmm[t * DIM + tid] + bta[t * DIM + tid];
}

extern "C" void kernel_launch(void* const* d_in, const int* in_sizes, int n_in,
                              void* d_out, int out_size, void* d_ws, size_t ws_size,
                              hipStream_t stream) {
    const float* x      = (const float*)d_in[0];
    const int*   ntype  = (const int*)d_in[1];
    const int*   ei     = (const int*)d_in[2];
    const int*   etype  = (const int*)d_in[3];
    const int*   esign  = (const int*)d_in[4];
    const float* edist  = (const float*)d_in[5];
    const float* Wq     = (const float*)d_in[6];
    const float* bq     = (const float*)d_in[7];
    const float* Wk     = (const float*)d_in[8];
    const float* bk     = (const float*)d_in[9];
    const float* Wv     = (const float*)d_in[10];
    const float* bv     = (const float*)d_in[11];
    const float* rel_q  = (const float*)d_in[12];
    const float* rel_k  = (const float*)d_in[13];
    const float* rel_v  = (const float*)d_in[14];
    const float* skn    = (const float*)d_in[15];
    const float* svn    = (const float*)d_in[16];
    const float* rbias  = (const float*)d_in[17];
    const float* dalpha = (const float*)d_in[18];
    const float* dtau   = (const float*)d_in[19];
    const float* skip   = (const float*)d_in[20];
    const float* gmm    = (const float*)d_in[21];
    const float* bta    = (const float*)d_in[22];
    float* out = (float*)d_out;

    char* ws = (char*)d_ws;
    float*          Qf     = (float*)         (ws + 0);          // 25.6 MB
    unsigned short* K16    = (unsigned short*)(ws + 25600000);   // 12.8 MB
    unsigned short* V16    = (unsigned short*)(ws + 38400000);   // 12.8 MB
    unsigned short* xb     = (unsigned short*)(ws + 51200000);   // 12.8 MB
    unsigned short* Wt     = (unsigned short*)(ws + 64000000);   // 393 KB
    float*          wqk    = (float*)         (ws + 64500000);   // 12 KB (24x128)
    float*          wvt    = (float*)         (ws + 64520000);   // 12 KB
    int*            cnt    = (int*)           (ws + 64600000);   // N
    int*            offs   = (int*)           (ws + 64900000);   // N+1
    int*            ecur   = (int*)           (ws + 65200000);   // N
    int*            bsum   = (int*)           (ws + 65500000);   // 256
    int*            bofs   = (int*)           (ws + 65502000);   // 256
    int*            packed = (int*)           (ws + 65600000);   // E
    float*          phi_s  = (float*)         (ws + 68800000);   // E
    int*            opad   = (int*)           (ws + 72100000);   // NPAD_MAX
    int*            bhist  = (int*)           (ws + 72400000);   // 196*4
    int*            bbase  = (int*)           (ws + 72410000);   // 196*4
    int*            pb     = (int*)           (ws + 72420000);   // 5

    hipMemsetAsync(cnt, 0, (size_t)N_NODES * 4, stream);
    hipMemsetAsync(opad, 0xFF, (size_t)NPAD_MAX * 4, stream);

    // node bucketing (padded) + prep
    k_typehist <<<NBLK_SCAN, 256, 0, stream>>>(ntype, bhist);
    k_typescan <<<1, 1024, 0, stream>>>(bhist, bbase, pb);
    k_scatter2 <<<NBLK_SCAN, 256, 0, stream>>>(ntype, bbase, opad);
    k_xcvt     <<<(N_NODES * DIM / 4 + 255) / 256, 256, 0, stream>>>(x, xb);
    k_wt       <<<NT * 3 * DIM, 128, 0, stream>>>(Wq, Wk, Wv, Wt);
    k_tbl      <<<(3 * NR * DIM + 255) / 256, 256, 0, stream>>>(rel_q, rel_k, rel_v, skn, svn, wqk, wvt);

    // MFMA projection
    k_projm <<<dim3(NTILE_ROW, 6), 256, 0, stream>>>(xb, Wt, opad, pb, bq, bk, bv, Qf, K16, V16);

    // edge counting-sort by destination
    k_hist  <<<(N_EDGES + 255) / 256, 256, 0, stream>>>(ei, cnt);
    k_scan1 <<<NBLK_SCAN, 256, 0, stream>>>(cnt, offs, bsum);
    k_scan2 <<<1, 256, 0, stream>>>(bsum, bofs, offs);
    k_scan3 <<<NBLK_SCAN, 256, 0, stream>>>(offs, bofs, ecur);
    k_esort <<<(N_EDGES + 255) / 256, 256, 0, stream>>>(ei, etype, esign, edist, dalpha, dtau,
                                                        ecur, packed, phi_s);

    // fused attention + aggregation + skip + LayerNorm
    k_attn <<<N_NODES, 128, 0, stream>>>(Qf, (const unsigned int*)K16, (const unsigned int*)V16,
                                         x, ntype, offs, packed, phi_s,
                                         wqk, wvt, rbias, skip, gmm, bta, out);
}

// Round 5
// 250.585 us; speedup vs baseline: 5.1981x; 1.2470x over previous
//
#include <hip/hip_runtime.h>

#define N_NODES 50000
#define N_EDGES 800000
#define DIM 128
#define NT 4
#define NR 6
#define NH 8
#define NBLK_SCAN ((N_NODES + 255) / 256)   // 196
#define NTILE_ROW 3129                      // ceil((N + 4*15)/16)
#define NPAD_MAX (NTILE_ROW * 16)           // 50064

#define XCVT_N (N_NODES * DIM / 4)          // 1,600,000 float4s
#define WT_N   (NT * 3 * DIM * DIM)         // 196,608 elems
#define WCOMB_N (24 * 64)                   // 1,536 float4s
#define PREP_TOTAL (XCVT_N + WT_N + WCOMB_N)

typedef __attribute__((ext_vector_type(8))) short bf16x8;
typedef __attribute__((ext_vector_type(4))) float f32x4;

__device__ __forceinline__ unsigned short f2bf(float f) {
    unsigned int u = __float_as_uint(f);
    return (unsigned short)((u + 0x7fffu + ((u >> 16) & 1u)) >> 16);
}

__device__ __forceinline__ int sign_index(int s) {
    // es = where((s < -1)|(s==0), -2, clip(s,-1,1)); idx: -1->0, 1->1, else->2
    if (s < -1 || s == 0) return 2;
    return (s == -1) ? 0 : 1;
}

// ---------------- node bucketing by type (contention-free, padded to x16) ----------------
__global__ __launch_bounds__(256) void k_typehist(const int* __restrict__ ntype,
                                                  int* __restrict__ bhist) {
    __shared__ int h[NT];
    if (threadIdx.x < NT) h[threadIdx.x] = 0;
    __syncthreads();
    int n = blockIdx.x * 256 + threadIdx.x;
    if (n < N_NODES) atomicAdd(&h[ntype[n]], 1);
    __syncthreads();
    if (threadIdx.x < NT) bhist[blockIdx.x * NT + threadIdx.x] = h[threadIdx.x];
}

__global__ __launch_bounds__(1024) void k_typescan(const int* __restrict__ bhist,
                                                   int* __restrict__ bbase,
                                                   int* __restrict__ pb_g) {
    __shared__ int s[1024];
    __shared__ int pb[NT + 1];
    int tid = threadIdx.x;
    int t = tid / NBLK_SCAN;
    int b = tid - t * NBLK_SCAN;
    int v = (tid < NT * NBLK_SCAN) ? bhist[b * NT + t] : 0;
    s[tid] = v;
    __syncthreads();
    for (int d = 1; d < 1024; d <<= 1) {
        int add = (tid >= d) ? s[tid - d] : 0;
        __syncthreads();
        s[tid] += add;
        __syncthreads();
    }
    if (tid == 0) {
        int acc = 0;
        for (int tt = 0; tt < NT; ++tt) {
            pb[tt] = acc;
            int tot = s[(tt + 1) * NBLK_SCAN - 1] - (tt ? s[tt * NBLK_SCAN - 1] : 0);
            acc += ((tot + 15) >> 4) << 4;
        }
        pb[NT] = acc;
    }
    __syncthreads();
    if (tid < NT * NBLK_SCAN) {
        int excl = s[tid] - v;
        int base_t = t ? s[t * NBLK_SCAN - 1] : 0;
        bbase[b * NT + t] = pb[t] + (excl - base_t);
    }
    if (tid <= NT) pb_g[tid] = pb[tid];
}

__global__ __launch_bounds__(256) void k_scatter2(const int* __restrict__ ntype,
                                                  const int* __restrict__ bbase,
                                                  int* __restrict__ order_pad) {
    __shared__ int cur[NT];
    if (threadIdx.x < NT) cur[threadIdx.x] = bbase[blockIdx.x * NT + threadIdx.x];
    __syncthreads();
    int n = blockIdx.x * 256 + threadIdx.x;
    if (n < N_NODES) {
        int t = ntype[n];
        int pos = atomicAdd(&cur[t], 1);   // LDS atomic
        order_pad[pos] = n;
    }
}

// ---------------- fused prep: x->bf16 | W->bf16 transposed | combined weight table ----------------
// wcomb[cmb][lane] = {wqk(2l), wqk(2l+1), wv(2l), wv(2l+1)}, cmb = sidx*8+et
__global__ __launch_bounds__(256) void k_prep(
    const float* __restrict__ x,
    const float* __restrict__ Wq, const float* __restrict__ Wk, const float* __restrict__ Wv,
    const float* __restrict__ rel_q, const float* __restrict__ rel_k,
    const float* __restrict__ rel_v,
    const float* __restrict__ skn, const float* __restrict__ svn,
    unsigned short* __restrict__ xb, unsigned short* __restrict__ Wt,
    float4* __restrict__ wcomb)
{
    int i = blockIdx.x * 256 + threadIdx.x;
    if (i < XCVT_N) {
        float4 v = ((const float4*)x)[i];
        ushort4 o;
        o.x = f2bf(v.x); o.y = f2bf(v.y); o.z = f2bf(v.z); o.w = f2bf(v.w);
        ((ushort4*)xb)[i] = o;
    } else if (i < XCVT_N + WT_N) {
        int j = i - XCVT_N;            // Wt[ts][out][in], ts = t*3+sel
        int in = j & 127;
        int blk = j >> 7;
        int out = blk & 127;
        int ts = blk >> 7;
        int sel = ts % 3, t = ts / 3;
        const float* W = sel == 0 ? Wq : (sel == 1 ? Wk : Wv);
        Wt[j] = f2bf(W[((size_t)t * DIM + in) * DIM + out]);
    } else if (i < PREP_TOTAL) {
        int j = i - XCVT_N - WT_N;     // cmb*64 + lane
        int lane = j & 63;
        int cmb = j >> 6;
        int et = cmb & 7, sidx = cmb >> 3;
        if (et < NR) {
            int o0 = lane * 2, o1 = o0 + 1;
            int h = o0 >> 4;
            int rb0 = (et * NH + h) * 16 + (o0 & 15);
            int rb1 = (et * NH + h) * 16 + (o1 & 15);
            float sgk0 = sidx == 0 ? -1.f : (sidx == 1 ? 1.f : skn[o0]);
            float sgk1 = sidx == 0 ? -1.f : (sidx == 1 ? 1.f : skn[o1]);
            float sgv0 = sidx == 0 ? -1.f : (sidx == 1 ? 1.f : svn[o0]);
            float sgv1 = sidx == 0 ? -1.f : (sidx == 1 ? 1.f : svn[o1]);
            float4 w;
            w.x = rel_q[rb0] * rel_k[rb0] * sgk0 * 0.25f;
            w.y = rel_q[rb1] * rel_k[rb1] * sgk1 * 0.25f;
            w.z = rel_v[rb0] * sgv0;
            w.w = rel_v[rb1] * sgv1;
            wcomb[cmb * 64 + lane] = w;
        }
    }
}

// ---------------- MFMA projection: Q (f32), interleaved K/V (bf16) ----------------
// KVu layout per node: 64 pairs x {k0,k1,v0,v1} ushorts (512B/row)
__global__ __launch_bounds__(256) void k_projm(
    const unsigned short* __restrict__ xb, const unsigned short* __restrict__ Wt,
    const int* __restrict__ order_pad, const int* __restrict__ pb_g,
    const float* __restrict__ bq, const float* __restrict__ bk, const float* __restrict__ bv,
    float* __restrict__ Qf, unsigned short* __restrict__ KVu)
{
    int row0 = blockIdx.x * 16;
    if (row0 >= pb_g[NT]) return;
    int t = (row0 >= pb_g[3]) ? 3 : (row0 >= pb_g[2]) ? 2 : (row0 >= pb_g[1]) ? 1 : 0;
    int wave = threadIdx.x >> 6, lane = threadIdx.x & 63;
    int ocol = blockIdx.y * 64 + wave * 16 + (lane & 15);
    int sel = ocol >> 7, wcol = ocol & 127;
    int arow = row0 + (lane & 15);
    int nidA = order_pad[arow];
    const unsigned short* xrow = xb + (size_t)(nidA < 0 ? 0 : nidA) * DIM;
    const unsigned short* wrow = Wt + ((size_t)(t * 3 + sel) * DIM + wcol) * DIM;
    int ko = (lane >> 4) * 8;
    f32x4 acc = {0.f, 0.f, 0.f, 0.f};
    #pragma unroll
    for (int kt = 0; kt < 4; ++kt) {
        bf16x8 a = *(const bf16x8*)(xrow + kt * 32 + ko);
        bf16x8 b = *(const bf16x8*)(wrow + kt * 32 + ko);
        acc = __builtin_amdgcn_mfma_f32_16x16x32_bf16(a, b, acc, 0, 0, 0);
    }
    const float* bias_p = sel == 0 ? bq : (sel == 1 ? bk : bv);
    float bias = bias_p[t * DIM + wcol];
    #pragma unroll
    for (int r = 0; r < 4; ++r) {
        int drow = row0 + (lane >> 4) * 4 + r;
        int nid = order_pad[drow];
        if (nid < 0) continue;
        float v = acc[r] + bias;
        if (sel == 0) Qf[(size_t)nid * DIM + wcol] = v;
        else KVu[(size_t)nid * 256 + (wcol >> 1) * 4 + (wcol & 1) + (sel == 2 ? 2 : 0)] = f2bf(v);
    }
}

// ---------------- edge counting sort by dst (atomic only in hist) ----------------
__global__ void k_hist2(const int* __restrict__ ei, int* __restrict__ cnt,
                        int* __restrict__ posw) {
    int e = blockIdx.x * blockDim.x + threadIdx.x;
    if (e < N_EDGES) posw[e] = atomicAdd(&cnt[ei[N_EDGES + e]], 1);
}

__global__ __launch_bounds__(256) void k_scan1(const int* __restrict__ cnt,
                                               int* __restrict__ offs, int* __restrict__ bsum) {
    __shared__ int s[256];
    int i = blockIdx.x * 256 + threadIdx.x;
    int v = (i < N_NODES) ? cnt[i] : 0;
    s[threadIdx.x] = v;
    __syncthreads();
    for (int d = 1; d < 256; d <<= 1) {
        int add = (threadIdx.x >= d) ? s[threadIdx.x - d] : 0;
        __syncthreads();
        s[threadIdx.x] += add;
        __syncthreads();
    }
    if (i < N_NODES) offs[i] = s[threadIdx.x] - v;
    if (threadIdx.x == 255) bsum[blockIdx.x] = s[255];
}

__global__ __launch_bounds__(256) void k_scan2(const int* __restrict__ bsum,
                                               int* __restrict__ bofs, int* __restrict__ offs) {
    __shared__ int s[256];
    int t = threadIdx.x;
    int v = (t < NBLK_SCAN) ? bsum[t] : 0;
    s[t] = v;
    __syncthreads();
    for (int d = 1; d < 256; d <<= 1) {
        int add = (t >= d) ? s[t - d] : 0;
        __syncthreads();
        s[t] += add;
        __syncthreads();
    }
    if (t < NBLK_SCAN) bofs[t] = s[t] - v;
    if (t == 0) offs[N_NODES] = N_EDGES;
}

__global__ void k_scan3(int* __restrict__ offs, const int* __restrict__ bofs) {
    int i = blockIdx.x * blockDim.x + threadIdx.x;
    if (i < N_NODES) offs[i] += bofs[i >> 8];
}

// emit edge records {src|cmb<<16, phi} into dst-sorted slots — no atomics
__global__ void k_emit(const int* __restrict__ ei, const int* __restrict__ etype,
                       const int* __restrict__ esign, const float* __restrict__ edist,
                       const float* __restrict__ dalpha, const float* __restrict__ dtau,
                       const int* __restrict__ offs, const int* __restrict__ posw,
                       int2* __restrict__ edata) {
    int e = blockIdx.x * blockDim.x + threadIdx.x;
    if (e >= N_EDGES) return;
    int dst = ei[N_EDGES + e];
    int pos = offs[dst] + posw[e];
    int cmb = sign_index(esign[e]) * 8 + etype[e];
    float phi = dalpha[0] * __expf(-edist[e] / (dtau[0] + 1e-9f));
    edata[pos] = make_int2(ei[e] | (cmb << 16), __float_as_int(phi));
}

// ---------------- fused attention + aggregation + skip + LN ----------------
// 256 threads = 4 waves; ONE wave per node; lane holds elems 2l,2l+1; 2-edge unroll
__global__ __launch_bounds__(256) void k_attn(
    const float* __restrict__ Qf, const uint2* __restrict__ KV,
    const float* __restrict__ x, const int* __restrict__ ntype,
    const int* __restrict__ offs, const int2* __restrict__ edata,
    const float4* __restrict__ wcomb, const float* __restrict__ rbias,
    const float* __restrict__ skip, const float* __restrict__ gmm,
    const float* __restrict__ bta, float* __restrict__ out)
{
    __shared__ float rb_s[NR * NH];
    if (threadIdx.x < NR * NH) rb_s[threadIdx.x] = rbias[threadIdx.x];
    __syncthreads();
    const int wave = threadIdx.x >> 6, lane = threadIdx.x & 63;
    const int n = blockIdx.x * 4 + wave;
    const int h = lane >> 3;
    const int beg = offs[n], end = offs[n + 1];

    const float2 q2 = ((const float2*)(Qf + (size_t)n * DIM))[lane];

    // scores bounded; exp without max-shift is safe in f32 (softmax shift-invariant)
    float Z = 0.f, a0 = 0.f, a1 = 0.f;
    int j = beg;
    for (; j + 1 < end; j += 2) {
        int2 rA = edata[j];
        int2 rB = edata[j + 1];
        int srcA = rA.x & 0xffff, cmbA = rA.x >> 16;
        int srcB = rB.x & 0xffff, cmbB = rB.x >> 16;
        uint2 kvA = KV[srcA * 64 + lane];
        uint2 kvB = KV[srcB * 64 + lane];
        float4 wA = wcomb[cmbA * 64 + lane];
        float4 wB = wcomb[cmbB * 64 + lane];
        float kA0 = __uint_as_float(kvA.x << 16);
        float kA1 = __uint_as_float(kvA.x & 0xffff0000u);
        float kB0 = __uint_as_float(kvB.x << 16);
        float kB1 = __uint_as_float(kvB.x & 0xffff0000u);
        float pA = fmaf(q2.y * wA.y, kA1, (q2.x * wA.x) * kA0);
        float pB = fmaf(q2.y * wB.y, kB1, (q2.x * wB.x) * kB0);
        pA += __shfl_xor(pA, 1, 8);  pB += __shfl_xor(pB, 1, 8);
        pA += __shfl_xor(pA, 2, 8);  pB += __shfl_xor(pB, 2, 8);
        pA += __shfl_xor(pA, 4, 8);  pB += __shfl_xor(pB, 4, 8);
        float exA = __expf(pA + __int_as_float(rA.y) + rb_s[(cmbA & 7) * NH + h]);
        float exB = __expf(pB + __int_as_float(rB.y) + rb_s[(cmbB & 7) * NH + h]);
        float vA0 = __uint_as_float(kvA.y << 16) * wA.z;
        float vA1 = __uint_as_float(kvA.y & 0xffff0000u) * wA.w;
        float vB0 = __uint_as_float(kvB.y << 16) * wB.z;
        float vB1 = __uint_as_float(kvB.y & 0xffff0000u) * wB.w;
        Z += exA + exB;
        a0 = fmaf(vA0, exA, a0);
        a1 = fmaf(vA1, exA, a1);
        a0 = fmaf(vB0, exB, a0);
        a1 = fmaf(vB1, exB, a1);
    }
    if (j < end) {
        int2 rA = edata[j];
        int srcA = rA.x & 0xffff, cmbA = rA.x >> 16;
        uint2 kvA = KV[srcA * 64 + lane];
        float4 wA = wcomb[cmbA * 64 + lane];
        float kA0 = __uint_as_float(kvA.x << 16);
        float kA1 = __uint_as_float(kvA.x & 0xffff0000u);
        float pA = fmaf(q2.y * wA.y, kA1, (q2.x * wA.x) * kA0);
        pA += __shfl_xor(pA, 1, 8);
        pA += __shfl_xor(pA, 2, 8);
        pA += __shfl_xor(pA, 4, 8);
        float exA = __expf(pA + __int_as_float(rA.y) + rb_s[(cmbA & 7) * NH + h]);
        float vA0 = __uint_as_float(kvA.y << 16) * wA.z;
        float vA1 = __uint_as_float(kvA.y & 0xffff0000u) * wA.w;
        Z += exA;
        a0 = fmaf(vA0, exA, a0);
        a1 = fmaf(vA1, exA, a1);
    }

    float rz = 1.f / (Z + 1e-9f);
    float oo0 = a0 * rz, oo1 = a1 * rz;

    int t = ntype[n];
    float alpha = 1.f / (1.f + __expf(-skip[t]));
    float2 x2 = ((const float2*)(x + (size_t)n * DIM))[lane];
    float mix0 = fmaf(alpha, oo0 - x2.x, x2.x);
    float mix1 = fmaf(alpha, oo1 - x2.y, x2.y);

    float s = mix0 + mix1, s2 = mix0 * mix0 + mix1 * mix1;
    #pragma unroll
    for (int d = 32; d >= 1; d >>= 1) {
        s += __shfl_xor(s, d, 64);
        s2 += __shfl_xor(s2, d, 64);
    }
    float mu = s * (1.f / DIM);
    float var = s2 * (1.f / DIM) - mu * mu;
    float rstd = rsqrtf(var + 1e-5f);
    float2 g2 = ((const float2*)(gmm + t * DIM))[lane];
    float2 b2 = ((const float2*)(bta + t * DIM))[lane];
    float2 o2;
    o2.x = (mix0 - mu) * rstd * g2.x + b2.x;
    o2.y = (mix1 - mu) * rstd * g2.y + b2.y;
    ((float2*)(out + (size_t)n * DIM))[lane] = o2;
}

extern "C" void kernel_launch(void* const* d_in, const int* in_sizes, int n_in,
                              void* d_out, int out_size, void* d_ws, size_t ws_size,
                              hipStream_t stream) {
    const float* x      = (const float*)d_in[0];
    const int*   ntype  = (const int*)d_in[1];
    const int*   ei     = (const int*)d_in[2];
    const int*   etype  = (const int*)d_in[3];
    const int*   esign  = (const int*)d_in[4];
    const float* edist  = (const float*)d_in[5];
    const float* Wq     = (const float*)d_in[6];
    const float* bq     = (const float*)d_in[7];
    const float* Wk     = (const float*)d_in[8];
    const float* bk     = (const float*)d_in[9];
    const float* Wv     = (const float*)d_in[10];
    const float* bv     = (const float*)d_in[11];
    const float* rel_q  = (const float*)d_in[12];
    const float* rel_k  = (const float*)d_in[13];
    const float* rel_v  = (const float*)d_in[14];
    const float* skn    = (const float*)d_in[15];
    const float* svn    = (const float*)d_in[16];
    const float* rbias  = (const float*)d_in[17];
    const float* dalpha = (const float*)d_in[18];
    const float* dtau   = (const float*)d_in[19];
    const float* skip   = (const float*)d_in[20];
    const float* gmm    = (const float*)d_in[21];
    const float* bta    = (const float*)d_in[22];
    float* out = (float*)d_out;

    char* ws = (char*)d_ws;
    float*          Qf     = (float*)         (ws + 0);          // 25.6 MB
    unsigned short* KVu    = (unsigned short*)(ws + 25600000);   // 25.6 MB interleaved K/V
    unsigned short* xb     = (unsigned short*)(ws + 51200000);   // 12.8 MB
    unsigned short* Wt     = (unsigned short*)(ws + 64000000);   // 393 KB
    float4*         wcomb  = (float4*)        (ws + 64500000);   // 24.6 KB
    int*            cnt    = (int*)           (ws + 64600000);   // N
    int*            offs   = (int*)           (ws + 64900000);   // N+1
    int*            bsum   = (int*)           (ws + 65200000);   // 256
    int*            bofs   = (int*)           (ws + 65210000);   // 256
    int*            posw   = (int*)           (ws + 65300000);   // E = 3.2 MB
    int2*           edata  = (int2*)          (ws + 68600000);   // E*8 = 6.4 MB
    int*            opad   = (int*)           (ws + 75000000);   // NPAD_MAX
    int*            bhist  = (int*)           (ws + 75300000);   // 196*4
    int*            bbase  = (int*)           (ws + 75310000);   // 196*4
    int*            pb     = (int*)           (ws + 75320000);   // 5

    hipMemsetAsync(cnt, 0, (size_t)N_NODES * 4, stream);
    hipMemsetAsync(opad, 0xFF, (size_t)NPAD_MAX * 4, stream);

    // node bucketing (padded) + fused prep
    k_typehist <<<NBLK_SCAN, 256, 0, stream>>>(ntype, bhist);
    k_typescan <<<1, 1024, 0, stream>>>(bhist, bbase, pb);
    k_scatter2 <<<NBLK_SCAN, 256, 0, stream>>>(ntype, bbase, opad);
    k_prep     <<<(PREP_TOTAL + 255) / 256, 256, 0, stream>>>(x, Wq, Wk, Wv, rel_q, rel_k, rel_v,
                                                              skn, svn, xb, Wt, wcomb);

    // MFMA projection
    k_projm <<<dim3(NTILE_ROW, 6), 256, 0, stream>>>(xb, Wt, opad, pb, bq, bk, bv, Qf, KVu);

    // edge counting-sort by destination (single atomic pass)
    k_hist2 <<<(N_EDGES + 255) / 256, 256, 0, stream>>>(ei, cnt, posw);
    k_scan1 <<<NBLK_SCAN, 256, 0, stream>>>(cnt, offs, bsum);
    k_scan2 <<<1, 256, 0, stream>>>(bsum, bofs, offs);
    k_scan3 <<<NBLK_SCAN, 256, 0, stream>>>(offs, bofs);
    k_emit  <<<(N_EDGES + 255) / 256, 256, 0, stream>>>(ei, etype, esign, edist, dalpha, dtau,
                                                        offs, posw, edata);

    // fused attention + aggregation + skip + LayerNorm (1 wave per node)
    k_attn <<<N_NODES / 4, 256, 0, stream>>>(Qf, (const uint2*)KVu, x, ntype, offs, edata,
                                             wcomb, rbias, skip, gmm, bta, out);
}

// Round 6
// 230.004 us; speedup vs baseline: 5.6632x; 1.0895x over previous
//
#include <hip/hip_runtime.h>

#define N_NODES 50000
#define N_EDGES 800000
#define DIM 128
#define NT 4
#define NR 6
#define NH 8
#define NBLK_SCAN ((N_NODES + 255) / 256)   // 196
#define NTILE_ROW 3129                      // ceil((N + 4*15)/16)
#define NPAD_MAX (NTILE_ROW * 16)           // 50064

#define XCVT_N (N_NODES * DIM / 4)          // 1,600,000 float4s
#define WT_N   (NT * 3 * DIM * DIM)         // 196,608 elems
#define WCOMB_N (24 * 64)                   // 1,536 float4s
#define PREP_TOTAL (XCVT_N + WT_N + WCOMB_N)
#define PREP_BLOCKS ((PREP_TOTAL + 255) / 256)          // 7024
#define HIST_BLOCKS (N_EDGES / 256)                     // 3125
#define MID_PREP_BASE NBLK_SCAN                         // 196
#define MID_HIST_BASE (NBLK_SCAN + PREP_BLOCKS)         // 7220
#define MID_BLOCKS (MID_HIST_BASE + HIST_BLOCKS)        // 10345

typedef __attribute__((ext_vector_type(8))) short bf16x8;
typedef __attribute__((ext_vector_type(4))) float f32x4;

__device__ __forceinline__ unsigned short f2bf(float f) {
    unsigned int u = __float_as_uint(f);
    return (unsigned short)((u + 0x7fffu + ((u >> 16) & 1u)) >> 16);
}

__device__ __forceinline__ int sign_index(int s) {
    // es = where((s < -1)|(s==0), -2, clip(s,-1,1)); idx: -1->0, 1->1, else->2
    if (s < -1 || s == 0) return 2;
    return (s == -1) ? 0 : 1;
}

// ---------------- node type histogram + buffer inits (fused memsets) ----------------
__global__ __launch_bounds__(256) void k_typehist(const int* __restrict__ ntype,
                                                  int* __restrict__ bhist,
                                                  int* __restrict__ cnt,
                                                  int* __restrict__ opad) {
    __shared__ int h[NT];
    if (threadIdx.x < NT) h[threadIdx.x] = 0;
    __syncthreads();
    int n = blockIdx.x * 256 + threadIdx.x;
    if (n < N_NODES) { atomicAdd(&h[ntype[n]], 1); cnt[n] = 0; }
    if (n < NPAD_MAX) opad[n] = -1;
    __syncthreads();
    if (threadIdx.x < NT) bhist[blockIdx.x * NT + threadIdx.x] = h[threadIdx.x];
}

// scan block histograms (type-major) -> per-(block,type) bases with x16-padded type bases
__global__ __launch_bounds__(1024) void k_typescan(const int* __restrict__ bhist,
                                                   int* __restrict__ bbase,
                                                   int* __restrict__ pb_g) {
    __shared__ int s[1024];
    __shared__ int pb[NT + 1];
    int tid = threadIdx.x;
    int t = tid / NBLK_SCAN;
    int b = tid - t * NBLK_SCAN;
    int v = (tid < NT * NBLK_SCAN) ? bhist[b * NT + t] : 0;
    s[tid] = v;
    __syncthreads();
    for (int d = 1; d < 1024; d <<= 1) {
        int add = (tid >= d) ? s[tid - d] : 0;
        __syncthreads();
        s[tid] += add;
        __syncthreads();
    }
    if (tid == 0) {
        int acc = 0;
        for (int tt = 0; tt < NT; ++tt) {
            pb[tt] = acc;
            int tot = s[(tt + 1) * NBLK_SCAN - 1] - (tt ? s[tt * NBLK_SCAN - 1] : 0);
            acc += ((tot + 15) >> 4) << 4;
        }
        pb[NT] = acc;
    }
    __syncthreads();
    if (tid < NT * NBLK_SCAN) {
        int excl = s[tid] - v;
        int base_t = t ? s[t * NBLK_SCAN - 1] : 0;
        bbase[b * NT + t] = pb[t] + (excl - base_t);
    }
    if (tid <= NT) pb_g[tid] = pb[tid];
}

// ---------------- fused middle stage: scatter2 | prep | hist2 (independent works) ----------------
__global__ __launch_bounds__(256) void k_mid(
    // scatter2
    const int* __restrict__ ntype, const int* __restrict__ bbase, int* __restrict__ order_pad,
    // prep
    const float* __restrict__ x,
    const float* __restrict__ Wq, const float* __restrict__ Wk, const float* __restrict__ Wv,
    const float* __restrict__ rel_q, const float* __restrict__ rel_k,
    const float* __restrict__ rel_v,
    const float* __restrict__ skn, const float* __restrict__ svn,
    unsigned short* __restrict__ xb, unsigned short* __restrict__ Wt,
    float4* __restrict__ wcomb,
    // hist2
    const int* __restrict__ ei, int* __restrict__ cnt, int* __restrict__ posw)
{
    int blk = blockIdx.x;
    if (blk < NBLK_SCAN) {
        // ---- scatter nodes into type-bucketed padded order ----
        __shared__ int cur[NT];
        if (threadIdx.x < NT) cur[threadIdx.x] = bbase[blk * NT + threadIdx.x];
        __syncthreads();
        int n = blk * 256 + threadIdx.x;
        if (n < N_NODES) {
            int t = ntype[n];
            int pos = atomicAdd(&cur[t], 1);   // LDS atomic
            order_pad[pos] = n;
        }
        return;
    }
    if (blk < MID_HIST_BASE) {
        // ---- prep: x->bf16 | W->bf16 transposed | combined weight table ----
        int i = (blk - MID_PREP_BASE) * 256 + threadIdx.x;
        if (i < XCVT_N) {
            float4 v = ((const float4*)x)[i];
            ushort4 o;
            o.x = f2bf(v.x); o.y = f2bf(v.y); o.z = f2bf(v.z); o.w = f2bf(v.w);
            ((ushort4*)xb)[i] = o;
        } else if (i < XCVT_N + WT_N) {
            int j = i - XCVT_N;            // Wt[ts][out][in], ts = t*3+sel
            int in = j & 127;
            int b2 = j >> 7;
            int out = b2 & 127;
            int ts = b2 >> 7;
            int sel = ts % 3, t = ts / 3;
            const float* W = sel == 0 ? Wq : (sel == 1 ? Wk : Wv);
            Wt[j] = f2bf(W[((size_t)t * DIM + in) * DIM + out]);
        } else if (i < PREP_TOTAL) {
            int j = i - XCVT_N - WT_N;     // cmb*64 + lane
            int lane = j & 63;
            int cmb = j >> 6;
            int et = cmb & 7, sidx = cmb >> 3;
            if (et < NR) {
                int o0 = lane * 2, o1 = o0 + 1;
                int h = o0 >> 4;
                int rb0 = (et * NH + h) * 16 + (o0 & 15);
                int rb1 = (et * NH + h) * 16 + (o1 & 15);
                float sgk0 = sidx == 0 ? -1.f : (sidx == 1 ? 1.f : skn[o0]);
                float sgk1 = sidx == 0 ? -1.f : (sidx == 1 ? 1.f : skn[o1]);
                float sgv0 = sidx == 0 ? -1.f : (sidx == 1 ? 1.f : svn[o0]);
                float sgv1 = sidx == 0 ? -1.f : (sidx == 1 ? 1.f : svn[o1]);
                float4 w;
                w.x = rel_q[rb0] * rel_k[rb0] * sgk0 * 0.25f;
                w.y = rel_q[rb1] * rel_k[rb1] * sgk1 * 0.25f;
                w.z = rel_v[rb0] * sgv0;
                w.w = rel_v[rb1] * sgv1;
                wcomb[cmb * 64 + lane] = w;
            }
        }
        return;
    }
    // ---- edge histogram with position-within return ----
    int e = (blk - MID_HIST_BASE) * 256 + threadIdx.x;
    if (e < N_EDGES) posw[e] = atomicAdd(&cnt[ei[N_EDGES + e]], 1);
}

// ---------------- MFMA projection (y<6) + scan1 (y==6) ----------------
// KVu layout per node: 64 pairs x {k0,k1,v0,v1} ushorts (512B/row)
__global__ __launch_bounds__(256) void k_projm(
    const unsigned short* __restrict__ xb, const unsigned short* __restrict__ Wt,
    const int* __restrict__ order_pad, const int* __restrict__ pb_g,
    const float* __restrict__ bq, const float* __restrict__ bk, const float* __restrict__ bv,
    float* __restrict__ Qf, unsigned short* __restrict__ KVu,
    const int* __restrict__ cnt, int* __restrict__ offs, int* __restrict__ bsum)
{
    if (blockIdx.y == 6) {
        if (blockIdx.x >= NBLK_SCAN) return;
        // ---- scan1: block-local exclusive scan of edge counts ----
        __shared__ int s[256];
        int i = blockIdx.x * 256 + threadIdx.x;
        int v = (i < N_NODES) ? cnt[i] : 0;
        s[threadIdx.x] = v;
        __syncthreads();
        for (int d = 1; d < 256; d <<= 1) {
            int add = (threadIdx.x >= d) ? s[threadIdx.x - d] : 0;
            __syncthreads();
            s[threadIdx.x] += add;
            __syncthreads();
        }
        if (i < N_NODES) offs[i] = s[threadIdx.x] - v;
        if (threadIdx.x == 255) bsum[blockIdx.x] = s[255];
        return;
    }
    int row0 = blockIdx.x * 16;
    if (row0 >= pb_g[NT]) return;
    int t = (row0 >= pb_g[3]) ? 3 : (row0 >= pb_g[2]) ? 2 : (row0 >= pb_g[1]) ? 1 : 0;
    int wave = threadIdx.x >> 6, lane = threadIdx.x & 63;
    int ocol = blockIdx.y * 64 + wave * 16 + (lane & 15);
    int sel = ocol >> 7, wcol = ocol & 127;
    int arow = row0 + (lane & 15);
    int nidA = order_pad[arow];
    const unsigned short* xrow = xb + (size_t)(nidA < 0 ? 0 : nidA) * DIM;
    const unsigned short* wrow = Wt + ((size_t)(t * 3 + sel) * DIM + wcol) * DIM;
    int ko = (lane >> 4) * 8;
    f32x4 acc = {0.f, 0.f, 0.f, 0.f};
    #pragma unroll
    for (int kt = 0; kt < 4; ++kt) {
        bf16x8 a = *(const bf16x8*)(xrow + kt * 32 + ko);
        bf16x8 b = *(const bf16x8*)(wrow + kt * 32 + ko);
        acc = __builtin_amdgcn_mfma_f32_16x16x32_bf16(a, b, acc, 0, 0, 0);
    }
    const float* bias_p = sel == 0 ? bq : (sel == 1 ? bk : bv);
    float bias = bias_p[t * DIM + wcol];
    #pragma unroll
    for (int r = 0; r < 4; ++r) {
        int drow = row0 + (lane >> 4) * 4 + r;
        int nid = order_pad[drow];
        if (nid < 0) continue;
        float v = acc[r] + bias;
        if (sel == 0) Qf[(size_t)nid * DIM + wcol] = v;
        else KVu[(size_t)nid * 256 + (wcol >> 1) * 4 + (wcol & 1) + (sel == 2 ? 2 : 0)] = f2bf(v);
    }
}

// scan of per-block sums; also writes the offs[N] boundary pre-compensated for bofs
__global__ __launch_bounds__(256) void k_scan2(const int* __restrict__ bsum,
                                               int* __restrict__ bofs, int* __restrict__ offs) {
    __shared__ int s[256];
    int t = threadIdx.x;
    int v = (t < NBLK_SCAN) ? bsum[t] : 0;
    s[t] = v;
    __syncthreads();
    for (int d = 1; d < 256; d <<= 1) {
        int add = (t >= d) ? s[t - d] : 0;
        __syncthreads();
        s[t] += add;
        __syncthreads();
    }
    if (t < NBLK_SCAN) {
        int b = s[t] - v;
        bofs[t] = b;
        if (t == NBLK_SCAN - 1) offs[N_NODES] = N_EDGES - b;  // so offs[N]+bofs[N>>8]==E
    }
}

// emit edge records {src|cmb<<16, phi} into dst-sorted slots — no atomics, bofs inline
__global__ void k_emit(const int* __restrict__ ei, const int* __restrict__ etype,
                       const int* __restrict__ esign, const float* __restrict__ edist,
                       const float* __restrict__ dalpha, const float* __restrict__ dtau,
                       const int* __restrict__ offs, const int* __restrict__ bofs,
                       const int* __restrict__ posw, int2* __restrict__ edata) {
    int e = blockIdx.x * blockDim.x + threadIdx.x;
    if (e >= N_EDGES) return;
    int dst = ei[N_EDGES + e];
    int pos = offs[dst] + bofs[dst >> 8] + posw[e];
    int cmb = sign_index(esign[e]) * 8 + etype[e];
    float phi = dalpha[0] * __expf(-edist[e] / (dtau[0] + 1e-9f));
    edata[pos] = make_int2(ei[e] | (cmb << 16), __float_as_int(phi));
}

// ---------------- fused attention + aggregation + skip + LN ----------------
// 256 threads = 4 waves; ONE wave per node; lane holds elems 2l,2l+1; 4-edge unroll
__global__ __launch_bounds__(256) void k_attn(
    const float* __restrict__ Qf, const uint2* __restrict__ KV,
    const float* __restrict__ x, const int* __restrict__ ntype,
    const int* __restrict__ offs, const int* __restrict__ bofs,
    const int2* __restrict__ edata,
    const float4* __restrict__ wcomb, const float* __restrict__ rbias,
    const float* __restrict__ skip, const float* __restrict__ gmm,
    const float* __restrict__ bta, float* __restrict__ out)
{
    __shared__ float rb_s[NR * NH];
    if (threadIdx.x < NR * NH) rb_s[threadIdx.x] = rbias[threadIdx.x];
    __syncthreads();
    const int wave = threadIdx.x >> 6, lane = threadIdx.x & 63;
    const int n = blockIdx.x * 4 + wave;
    const int h = lane >> 3;
    const int beg = offs[n] + bofs[n >> 8];
    const int end = offs[n + 1] + bofs[(n + 1) >> 8];

    const float2 q2 = ((const float2*)(Qf + (size_t)n * DIM))[lane];

    // scores bounded; exp without max-shift is safe in f32 (softmax shift-invariant)
    float Z = 0.f, a0 = 0.f, a1 = 0.f;
    int j = beg;
    for (; j + 3 < end; j += 4) {
        int2 rA = edata[j];
        int2 rB = edata[j + 1];
        int2 rC = edata[j + 2];
        int2 rD = edata[j + 3];
        int srcA = rA.x & 0xffff, cmbA = ((unsigned)rA.x) >> 16;
        int srcB = rB.x & 0xffff, cmbB = ((unsigned)rB.x) >> 16;
        int srcC = rC.x & 0xffff, cmbC = ((unsigned)rC.x) >> 16;
        int srcD = rD.x & 0xffff, cmbD = ((unsigned)rD.x) >> 16;
        uint2 kvA = KV[srcA * 64 + lane];
        uint2 kvB = KV[srcB * 64 + lane];
        uint2 kvC = KV[srcC * 64 + lane];
        uint2 kvD = KV[srcD * 64 + lane];
        float4 wA = wcomb[cmbA * 64 + lane];
        float4 wB = wcomb[cmbB * 64 + lane];
        float4 wC = wcomb[cmbC * 64 + lane];
        float4 wD = wcomb[cmbD * 64 + lane];
        float pA = fmaf(q2.y * wA.y, __uint_as_float(kvA.x & 0xffff0000u),
                        (q2.x * wA.x) * __uint_as_float(kvA.x << 16));
        float pB = fmaf(q2.y * wB.y, __uint_as_float(kvB.x & 0xffff0000u),
                        (q2.x * wB.x) * __uint_as_float(kvB.x << 16));
        float pC = fmaf(q2.y * wC.y, __uint_as_float(kvC.x & 0xffff0000u),
                        (q2.x * wC.x) * __uint_as_float(kvC.x << 16));
        float pD = fmaf(q2.y * wD.y, __uint_as_float(kvD.x & 0xffff0000u),
                        (q2.x * wD.x) * __uint_as_float(kvD.x << 16));
        pA += __shfl_xor(pA, 1, 8); pB += __shfl_xor(pB, 1, 8);
        pC += __shfl_xor(pC, 1, 8); pD += __shfl_xor(pD, 1, 8);
        pA += __shfl_xor(pA, 2, 8); pB += __shfl_xor(pB, 2, 8);
        pC += __shfl_xor(pC, 2, 8); pD += __shfl_xor(pD, 2, 8);
        pA += __shfl_xor(pA, 4, 8); pB += __shfl_xor(pB, 4, 8);
        pC += __shfl_xor(pC, 4, 8); pD += __shfl_xor(pD, 4, 8);
        float exA = __expf(pA + __int_as_float(rA.y) + rb_s[(cmbA & 7) * NH + h]);
        float exB = __expf(pB + __int_as_float(rB.y) + rb_s[(cmbB & 7) * NH + h]);
        float exC = __expf(pC + __int_as_float(rC.y) + rb_s[(cmbC & 7) * NH + h]);
        float exD = __expf(pD + __int_as_float(rD.y) + rb_s[(cmbD & 7) * NH + h]);
        Z += (exA + exB) + (exC + exD);
        a0 = fmaf(__uint_as_float(kvA.y << 16) * wA.z, exA, a0);
        a1 = fmaf(__uint_as_float(kvA.y & 0xffff0000u) * wA.w, exA, a1);
        a0 = fmaf(__uint_as_float(kvB.y << 16) * wB.z, exB, a0);
        a1 = fmaf(__uint_as_float(kvB.y & 0xffff0000u) * wB.w, exB, a1);
        a0 = fmaf(__uint_as_float(kvC.y << 16) * wC.z, exC, a0);
        a1 = fmaf(__uint_as_float(kvC.y & 0xffff0000u) * wC.w, exC, a1);
        a0 = fmaf(__uint_as_float(kvD.y << 16) * wD.z, exD, a0);
        a1 = fmaf(__uint_as_float(kvD.y & 0xffff0000u) * wD.w, exD, a1);
    }
    for (; j < end; ++j) {
        int2 rA = edata[j];
        int srcA = rA.x & 0xffff, cmbA = ((unsigned)rA.x) >> 16;
        uint2 kvA = KV[srcA * 64 + lane];
        float4 wA = wcomb[cmbA * 64 + lane];
        float pA = fmaf(q2.y * wA.y, __uint_as_float(kvA.x & 0xffff0000u),
                        (q2.x * wA.x) * __uint_as_float(kvA.x << 16));
        pA += __shfl_xor(pA, 1, 8);
        pA += __shfl_xor(pA, 2, 8);
        pA += __shfl_xor(pA, 4, 8);
        float exA = __expf(pA + __int_as_float(rA.y) + rb_s[(cmbA & 7) * NH + h]);
        Z += exA;
        a0 = fmaf(__uint_as_float(kvA.y << 16) * wA.z, exA, a0);
        a1 = fmaf(__uint_as_float(kvA.y & 0xffff0000u) * wA.w, exA, a1);
    }

    float rz = 1.f / (Z + 1e-9f);
    float oo0 = a0 * rz, oo1 = a1 * rz;

    int t = ntype[n];
    float alpha = 1.f / (1.f + __expf(-skip[t]));
    float2 x2 = ((const float2*)(x + (size_t)n * DIM))[lane];
    float mix0 = fmaf(alpha, oo0 - x2.x, x2.x);
    float mix1 = fmaf(alpha, oo1 - x2.y, x2.y);

    float s = mix0 + mix1, s2 = mix0 * mix0 + mix1 * mix1;
    #pragma unroll
    for (int d = 32; d >= 1; d >>= 1) {
        s += __shfl_xor(s, d, 64);
        s2 += __shfl_xor(s2, d, 64);
    }
    float mu = s * (1.f / DIM);
    float var = s2 * (1.f / DIM) - mu * mu;
    float rstd = rsqrtf(var + 1e-5f);
    float2 g2 = ((const float2*)(gmm + t * DIM))[lane];
    float2 b2 = ((const float2*)(bta + t * DIM))[lane];
    float2 o2;
    o2.x = (mix0 - mu) * rstd * g2.x + b2.x;
    o2.y = (mix1 - mu) * rstd * g2.y + b2.y;
    ((float2*)(out + (size_t)n * DIM))[lane] = o2;
}

extern "C" void kernel_launch(void* const* d_in, const int* in_sizes, int n_in,
                              void* d_out, int out_size, void* d_ws, size_t ws_size,
                              hipStream_t stream) {
    const float* x      = (const float*)d_in[0];
    const int*   ntype  = (const int*)d_in[1];
    const int*   ei     = (const int*)d_in[2];
    const int*   etype  = (const int*)d_in[3];
    const int*   esign  = (const int*)d_in[4];
    const float* edist  = (const float*)d_in[5];
    const float* Wq     = (const float*)d_in[6];
    const float* bq     = (const float*)d_in[7];
    const float* Wk     = (const float*)d_in[8];
    const float* bk     = (const float*)d_in[9];
    const float* Wv     = (const float*)d_in[10];
    const float* bv     = (const float*)d_in[11];
    const float* rel_q  = (const float*)d_in[12];
    const float* rel_k  = (const float*)d_in[13];
    const float* rel_v  = (const float*)d_in[14];
    const float* skn    = (const float*)d_in[15];
    const float* svn    = (const float*)d_in[16];
    const float* rbias  = (const float*)d_in[17];
    const float* dalpha = (const float*)d_in[18];
    const float* dtau   = (const float*)d_in[19];
    const float* skip   = (const float*)d_in[20];
    const float* gmm    = (const float*)d_in[21];
    const float* bta    = (const float*)d_in[22];
    float* out = (float*)d_out;

    char* ws = (char*)d_ws;
    float*          Qf     = (float*)         (ws + 0);          // 25.6 MB
    unsigned short* KVu    = (unsigned short*)(ws + 25600000);   // 25.6 MB interleaved K/V
    unsigned short* xb     = (unsigned short*)(ws + 51200000);   // 12.8 MB
    unsigned short* Wt     = (unsigned short*)(ws + 64000000);   // 393 KB
    float4*         wcomb  = (float4*)        (ws + 64500000);   // 24.6 KB
    int*            cnt    = (int*)           (ws + 64600000);   // N
    int*            offs   = (int*)           (ws + 64900000);   // N+1
    int*            bsum   = (int*)           (ws + 65200000);   // 256
    int*            bofs   = (int*)           (ws + 65210000);   // 256
    int*            posw   = (int*)           (ws + 65300000);   // E = 3.2 MB
    int2*           edata  = (int2*)          (ws + 68600000);   // E*8 = 6.4 MB
    int*            opad   = (int*)           (ws + 75000000);   // NPAD_MAX
    int*            bhist  = (int*)           (ws + 75300000);   // 196*4
    int*            bbase  = (int*)           (ws + 75310000);   // 196*4
    int*            pb     = (int*)           (ws + 75320000);   // 5

    // 1. type histogram + zero cnt + init opad (fused memsets)
    k_typehist <<<NBLK_SCAN, 256, 0, stream>>>(ntype, bhist, cnt, opad);
    // 2. type-bucket scan (padded to x16)
    k_typescan <<<1, 1024, 0, stream>>>(bhist, bbase, pb);
    // 3. fused: node scatter | prep (x->bf16, W^T->bf16, weight tables) | edge histogram
    k_mid <<<MID_BLOCKS, 256, 0, stream>>>(ntype, bbase, opad,
                                           x, Wq, Wk, Wv, rel_q, rel_k, rel_v, skn, svn,
                                           xb, Wt, wcomb,
                                           ei, cnt, posw);
    // 4. MFMA projection (y<6) + scan1 (y==6)
    k_projm <<<dim3(NTILE_ROW, 7), 256, 0, stream>>>(xb, Wt, opad, pb, bq, bk, bv,
                                                     Qf, KVu, cnt, offs, bsum);
    // 5. block-sum scan
    k_scan2 <<<1, 256, 0, stream>>>(bsum, bofs, offs);
    // 6. emit dst-sorted edge records
    k_emit <<<HIST_BLOCKS, 256, 0, stream>>>(ei, etype, esign, edist, dalpha, dtau,
                                             offs, bofs, posw, edata);
    // 7. fused attention + aggregation + skip + LayerNorm
    k_attn <<<N_NODES / 4, 256, 0, stream>>>(Qf, (const uint2*)KVu, x, ntype, offs, bofs,
                                             edata, wcomb, rbias, skip, gmm, bta, out);
}

// Round 7
// 182.835 us; speedup vs baseline: 7.1243x; 1.2580x over previous
//
#include <hip/hip_runtime.h>

#define N_NODES 50000
#define N_EDGES 800000
#define DIM 128
#define NT 4
#define NR 6
#define NH 8
#define NBLK_SCAN ((N_NODES + 255) / 256)   // 196
#define NTILE_ROW 3129                      // ceil((N + 4*15)/16)
#define NPAD_MAX (NTILE_ROW * 16)           // 50064

#define XCVT_N (N_NODES * DIM / 4)          // 1,600,000 float4s
#define WT_N   (NT * 3 * DIM * DIM)         // 196,608 elems
#define WCB_N  (24 * 32)                    // 768 uint4 entries
#define PREP_TOTAL (XCVT_N + WT_N + WCB_N)
#define PREP_BLOCKS ((PREP_TOTAL + 255) / 256)
#define HIST_BLOCKS (N_EDGES / 256)                     // 3125
#define MID_PREP_BASE NBLK_SCAN
#define MID_HIST_BASE (NBLK_SCAN + PREP_BLOCKS)
#define MID_BLOCKS (MID_HIST_BASE + HIST_BLOCKS)

typedef __attribute__((ext_vector_type(8))) short bf16x8;
typedef __attribute__((ext_vector_type(4))) float f32x4;

__device__ __forceinline__ unsigned short f2bf(float f) {
    unsigned int u = __float_as_uint(f);
    return (unsigned short)((u + 0x7fffu + ((u >> 16) & 1u)) >> 16);
}
__device__ __forceinline__ float blo(unsigned int u) { return __uint_as_float(u << 16); }
__device__ __forceinline__ float bhi(unsigned int u) { return __uint_as_float(u & 0xffff0000u); }

__device__ __forceinline__ int sign_index(int s) {
    // es = where((s < -1)|(s==0), -2, clip(s,-1,1)); idx: -1->0, 1->1, else->2
    if (s < -1 || s == 0) return 2;
    return (s == -1) ? 0 : 1;
}

// ---------------- node type histogram + buffer inits (fused memsets) ----------------
__global__ __launch_bounds__(256) void k_typehist(const int* __restrict__ ntype,
                                                  int* __restrict__ bhist,
                                                  int* __restrict__ cnt,
                                                  int* __restrict__ opad) {
    __shared__ int h[NT];
    if (threadIdx.x < NT) h[threadIdx.x] = 0;
    __syncthreads();
    int n = blockIdx.x * 256 + threadIdx.x;
    if (n < N_NODES) { atomicAdd(&h[ntype[n]], 1); cnt[n] = 0; }
    if (n < NPAD_MAX) opad[n] = -1;
    __syncthreads();
    if (threadIdx.x < NT) bhist[blockIdx.x * NT + threadIdx.x] = h[threadIdx.x];
}

// scan block histograms (type-major) -> per-(block,type) bases with x16-padded type bases
__global__ __launch_bounds__(1024) void k_typescan(const int* __restrict__ bhist,
                                                   int* __restrict__ bbase,
                                                   int* __restrict__ pb_g) {
    __shared__ int s[1024];
    __shared__ int pb[NT + 1];
    int tid = threadIdx.x;
    int t = tid / NBLK_SCAN;
    int b = tid - t * NBLK_SCAN;
    int v = (tid < NT * NBLK_SCAN) ? bhist[b * NT + t] : 0;
    s[tid] = v;
    __syncthreads();
    for (int d = 1; d < 1024; d <<= 1) {
        int add = (tid >= d) ? s[tid - d] : 0;
        __syncthreads();
        s[tid] += add;
        __syncthreads();
    }
    if (tid == 0) {
        int acc = 0;
        for (int tt = 0; tt < NT; ++tt) {
            pb[tt] = acc;
            int tot = s[(tt + 1) * NBLK_SCAN - 1] - (tt ? s[tt * NBLK_SCAN - 1] : 0);
            acc += ((tot + 15) >> 4) << 4;
        }
        pb[NT] = acc;
    }
    __syncthreads();
    if (tid < NT * NBLK_SCAN) {
        int excl = s[tid] - v;
        int base_t = t ? s[t * NBLK_SCAN - 1] : 0;
        bbase[b * NT + t] = pb[t] + (excl - base_t);
    }
    if (tid <= NT) pb_g[tid] = pb[tid];
}

// ---------------- fused middle stage: scatter2 | prep | hist2 ----------------
__global__ __launch_bounds__(256) void k_mid(
    const int* __restrict__ ntype, const int* __restrict__ bbase, int* __restrict__ order_pad,
    const float* __restrict__ x,
    const float* __restrict__ Wq, const float* __restrict__ Wk, const float* __restrict__ Wv,
    const float* __restrict__ rel_q, const float* __restrict__ rel_k,
    const float* __restrict__ rel_v,
    const float* __restrict__ skn, const float* __restrict__ svn,
    unsigned short* __restrict__ xb, unsigned short* __restrict__ Wt,
    uint4* __restrict__ wcb,
    const int* __restrict__ ei, int* __restrict__ cnt, int* __restrict__ posw)
{
    int blk = blockIdx.x;
    if (blk < NBLK_SCAN) {
        // ---- scatter nodes into type-bucketed padded order ----
        __shared__ int cur[NT];
        if (threadIdx.x < NT) cur[threadIdx.x] = bbase[blk * NT + threadIdx.x];
        __syncthreads();
        int n = blk * 256 + threadIdx.x;
        if (n < N_NODES) {
            int t = ntype[n];
            int pos = atomicAdd(&cur[t], 1);   // LDS atomic
            order_pad[pos] = n;
        }
        return;
    }
    if (blk < MID_HIST_BASE) {
        int i = (blk - MID_PREP_BASE) * 256 + threadIdx.x;
        if (i < XCVT_N) {
            float4 v = ((const float4*)x)[i];
            ushort4 o;
            o.x = f2bf(v.x); o.y = f2bf(v.y); o.z = f2bf(v.z); o.w = f2bf(v.w);
            ((ushort4*)xb)[i] = o;
        } else if (i < XCVT_N + WT_N) {
            int j = i - XCVT_N;            // Wt[ts][out][in], ts = t*3+sel
            int in = j & 127;
            int b2 = j >> 7;
            int out = b2 & 127;
            int ts = b2 >> 7;
            int sel = ts % 3, t = ts / 3;
            const float* W = sel == 0 ? Wq : (sel == 1 ? Wk : Wv);
            Wt[j] = f2bf(W[((size_t)t * DIM + in) * DIM + out]);
        } else if (i < PREP_TOTAL) {
            // wcb[cmb][p] = uint4 of bf16 pairs {wk(4p),wk(4p+1) | wv(4p),wv(4p+1) |
            //                                    wk(4p+2),wk(4p+3) | wv(4p+2),wv(4p+3)}
            int j = i - XCVT_N - WT_N;     // cmb*32 + p
            int p = j & 31;
            int cmb = j >> 5;
            int et = cmb & 7, sidx = cmb >> 3;
            if (et < NR) {
                int h = p >> 2;
                float wk[4], wv[4];
                #pragma unroll
                for (int q = 0; q < 4; ++q) {
                    int o = 4 * p + q;
                    int rb = (et * NH + h) * 16 + (o & 15);
                    float sgk = sidx == 0 ? -1.f : (sidx == 1 ? 1.f : skn[o]);
                    float sgv = sidx == 0 ? -1.f : (sidx == 1 ? 1.f : svn[o]);
                    wk[q] = rel_q[rb] * rel_k[rb] * sgk * 0.25f;
                    wv[q] = rel_v[rb] * sgv;
                }
                uint4 u;
                u.x = (unsigned)f2bf(wk[0]) | ((unsigned)f2bf(wk[1]) << 16);
                u.y = (unsigned)f2bf(wv[0]) | ((unsigned)f2bf(wv[1]) << 16);
                u.z = (unsigned)f2bf(wk[2]) | ((unsigned)f2bf(wk[3]) << 16);
                u.w = (unsigned)f2bf(wv[2]) | ((unsigned)f2bf(wv[3]) << 16);
                wcb[cmb * 32 + p] = u;
            }
        }
        return;
    }
    // ---- edge histogram with position-within return ----
    int e = (blk - MID_HIST_BASE) * 256 + threadIdx.x;
    if (e < N_EDGES) posw[e] = atomicAdd(&cnt[ei[N_EDGES + e]], 1);
}

// ---------------- MFMA projection (A-frag register reuse over 6 col groups) + scan1 ----------------
// KVu layout per node: 64 groups x {k0,k1,v0,v1} ushorts (512B/row)
__global__ __launch_bounds__(256) void k_projm(
    const unsigned short* __restrict__ xb, const unsigned short* __restrict__ Wt,
    const int* __restrict__ order_pad, const int* __restrict__ pb_g,
    const float* __restrict__ bq, const float* __restrict__ bk, const float* __restrict__ bv,
    float* __restrict__ Qf, unsigned short* __restrict__ KVu,
    const int* __restrict__ cnt, int* __restrict__ offs, int* __restrict__ bsum)
{
    int b = blockIdx.x;
    if (b >= NTILE_ROW) {
        // ---- scan1: block-local exclusive scan of edge counts ----
        int sb = b - NTILE_ROW;
        __shared__ int s[256];
        int i = sb * 256 + threadIdx.x;
        int v = (i < N_NODES) ? cnt[i] : 0;
        s[threadIdx.x] = v;
        __syncthreads();
        for (int d = 1; d < 256; d <<= 1) {
            int add = (threadIdx.x >= d) ? s[threadIdx.x - d] : 0;
            __syncthreads();
            s[threadIdx.x] += add;
            __syncthreads();
        }
        if (i < N_NODES) offs[i] = s[threadIdx.x] - v;
        if (threadIdx.x == 255) bsum[sb] = s[255];
        return;
    }
    int row0 = b * 16;
    if (row0 >= pb_g[NT]) return;
    int t = (row0 >= pb_g[3]) ? 3 : (row0 >= pb_g[2]) ? 2 : (row0 >= pb_g[1]) ? 1 : 0;
    int wave = threadIdx.x >> 6, lane = threadIdx.x & 63;
    int arow = row0 + (lane & 15);
    int nidA = order_pad[arow];
    const unsigned short* xrow = xb + (size_t)(nidA < 0 ? 0 : nidA) * DIM;
    int ko = (lane >> 4) * 8;
    bf16x8 afrag[4];
    #pragma unroll
    for (int kt = 0; kt < 4; ++kt) afrag[kt] = *(const bf16x8*)(xrow + kt * 32 + ko);

    #pragma unroll
    for (int g = 0; g < 6; ++g) {
        int ocol = g * 64 + wave * 16 + (lane & 15);
        int sel = ocol >> 7, wcol = ocol & 127;
        const unsigned short* wrow = Wt + ((size_t)(t * 3 + sel) * DIM + wcol) * DIM;
        f32x4 acc = {0.f, 0.f, 0.f, 0.f};
        #pragma unroll
        for (int kt = 0; kt < 4; ++kt) {
            bf16x8 bfr = *(const bf16x8*)(wrow + kt * 32 + ko);
            acc = __builtin_amdgcn_mfma_f32_16x16x32_bf16(afrag[kt], bfr, acc, 0, 0, 0);
        }
        const float* bias_p = sel == 0 ? bq : (sel == 1 ? bk : bv);
        float bias = bias_p[t * DIM + wcol];
        #pragma unroll
        for (int r = 0; r < 4; ++r) {
            int drow = row0 + (lane >> 4) * 4 + r;
            int nid = order_pad[drow];
            if (nid < 0) continue;
            float v = acc[r] + bias;
            if (sel == 0) Qf[(size_t)nid * DIM + wcol] = v;
            else KVu[(size_t)nid * 256 + (wcol >> 1) * 4 + (wcol & 1) + (sel == 2 ? 2 : 0)] = f2bf(v);
        }
    }
}

// scan of per-block sums; offs[N] boundary pre-compensated for bofs
__global__ __launch_bounds__(256) void k_scan2(const int* __restrict__ bsum,
                                               int* __restrict__ bofs, int* __restrict__ offs) {
    __shared__ int s[256];
    int t = threadIdx.x;
    int v = (t < NBLK_SCAN) ? bsum[t] : 0;
    s[t] = v;
    __syncthreads();
    for (int d = 1; d < 256; d <<= 1) {
        int add = (t >= d) ? s[t - d] : 0;
        __syncthreads();
        s[t] += add;
        __syncthreads();
    }
    if (t < NBLK_SCAN) {
        int b = s[t] - v;
        bofs[t] = b;
        if (t == NBLK_SCAN - 1) offs[N_NODES] = N_EDGES - b;  // so offs[N]+bofs[N>>8]==E
    }
}

// emit edge records {src|cmb<<16, phi} into dst-sorted slots — no atomics
__global__ void k_emit(const int* __restrict__ ei, const int* __restrict__ etype,
                       const int* __restrict__ esign, const float* __restrict__ edist,
                       const float* __restrict__ dalpha, const float* __restrict__ dtau,
                       const int* __restrict__ offs, const int* __restrict__ bofs,
                       const int* __restrict__ posw, int2* __restrict__ edata) {
    int e = blockIdx.x * blockDim.x + threadIdx.x;
    if (e >= N_EDGES) return;
    int dst = ei[N_EDGES + e];
    int pos = offs[dst] + bofs[dst >> 8] + posw[e];
    int cmb = sign_index(esign[e]) * 8 + etype[e];
    float phi = dalpha[0] * __expf(-edist[e] / (dtau[0] + 1e-9f));
    edata[pos] = make_int2(ei[e] | (cmb << 16), __float_as_int(phi));
}

// ---------------- fused attention + aggregation + skip + LN ----------------
// 256 threads = 4 waves; one wave per node. Each 32-lane HALF owns one edge;
// lane holds a 4-element quad (positions 4p..4p+3). Score reduce = 2 width-4 shuffles.
__global__ __launch_bounds__(256) void k_attn(
    const float4* __restrict__ Qf4, const uint4* __restrict__ KV,
    const uint4* __restrict__ WCB,
    const float* __restrict__ x, const int* __restrict__ ntype,
    const int* __restrict__ offs, const int* __restrict__ bofs,
    const int2* __restrict__ edata,
    const float* __restrict__ rbias, const float* __restrict__ skip,
    const float* __restrict__ gmm, const float* __restrict__ bta,
    float* __restrict__ out)
{
    __shared__ float rb_s[NR * NH];
    if (threadIdx.x < NR * NH) rb_s[threadIdx.x] = rbias[threadIdx.x];
    __syncthreads();
    const int wave = threadIdx.x >> 6, lane = threadIdx.x & 63;
    const int n = blockIdx.x * 4 + wave;
    const int p = lane & 31;          // position quad index (elems 4p..4p+3)
    const int hi = lane >> 5;         // which edge of the pair this half owns
    const int h = p >> 2;             // head
    const int beg = offs[n] + bofs[n >> 8];
    const int end = offs[n + 1] + bofs[(n + 1) >> 8];

    const float4 q4 = Qf4[(size_t)n * 32 + p];

    float Z = 0.f, a0 = 0.f, a1 = 0.f, a2 = 0.f, a3 = 0.f;

    // scores bounded; exp without max-shift is safe in f32 (softmax shift-invariant)
    auto process = [&](int2 r) {
        int src = r.x & 0xffff;
        unsigned cmb = ((unsigned)r.x) >> 16;
        uint4 kv = KV[(size_t)src * 32 + p];
        uint4 w = WCB[cmb * 32 + p];
        float pp = (q4.x * blo(w.x)) * blo(kv.x);
        pp = fmaf(q4.y * bhi(w.x), bhi(kv.x), pp);
        pp = fmaf(q4.z * blo(w.z), blo(kv.z), pp);
        pp = fmaf(q4.w * bhi(w.z), bhi(kv.z), pp);
        pp += __shfl_xor(pp, 1, 4);
        pp += __shfl_xor(pp, 2, 4);
        float ex = __expf(pp + rb_s[(cmb & 7) * NH + h] + __int_as_float(r.y));
        Z += ex;
        a0 = fmaf(blo(kv.y) * blo(w.y), ex, a0);
        a1 = fmaf(bhi(kv.y) * bhi(w.y), ex, a1);
        a2 = fmaf(blo(kv.w) * blo(w.w), ex, a2);
        a3 = fmaf(bhi(kv.w) * bhi(w.w), ex, a3);
    };

    int rem = end - beg;
    int j = beg;
    if (rem >= 4) {
        // 2-pair (4-edge) unroll with 1-iter-ahead edata prefetch:
        // current iteration's gathers issue immediately from registers.
        int2 r0 = edata[j + hi];
        int2 r1 = edata[j + 2 + hi];
        while (true) {
            int2 c0 = r0, c1 = r1;
            j += 4; rem -= 4;
            if (rem >= 4) { r0 = edata[j + hi]; r1 = edata[j + 2 + hi]; }
            process(c0);
            process(c1);
            if (rem < 4) break;
        }
    }
    while (rem >= 2) {
        int2 c = edata[j + hi];
        process(c);
        j += 2; rem -= 2;
    }
    if (rem) {
        // single leftover edge: both halves compute it; gate the hi half to zero
        int2 r = edata[j];
        int src = r.x & 0xffff;
        unsigned cmb = ((unsigned)r.x) >> 16;
        uint4 kv = KV[(size_t)src * 32 + p];
        uint4 w = WCB[cmb * 32 + p];
        float pp = (q4.x * blo(w.x)) * blo(kv.x);
        pp = fmaf(q4.y * bhi(w.x), bhi(kv.x), pp);
        pp = fmaf(q4.z * blo(w.z), blo(kv.z), pp);
        pp = fmaf(q4.w * bhi(w.z), bhi(kv.z), pp);
        pp += __shfl_xor(pp, 1, 4);
        pp += __shfl_xor(pp, 2, 4);
        float ex = __expf(pp + rb_s[(cmb & 7) * NH + h] + __int_as_float(r.y));
        ex = hi ? 0.f : ex;
        Z += ex;
        a0 = fmaf(blo(kv.y) * blo(w.y), ex, a0);
        a1 = fmaf(bhi(kv.y) * bhi(w.y), ex, a1);
        a2 = fmaf(blo(kv.w) * blo(w.w), ex, a2);
        a3 = fmaf(bhi(kv.w) * bhi(w.w), ex, a3);
    }

    // merge the two halves (lanes l and l+32 hold the same positions)
    Z  += __shfl_xor(Z, 32, 64);
    a0 += __shfl_xor(a0, 32, 64);
    a1 += __shfl_xor(a1, 32, 64);
    a2 += __shfl_xor(a2, 32, 64);
    a3 += __shfl_xor(a3, 32, 64);

    float rz = 1.f / (Z + 1e-9f);
    int t = ntype[n];
    float alpha = 1.f / (1.f + __expf(-skip[t]));
    float4 x4 = ((const float4*)x)[(size_t)n * 32 + p];
    float m0 = fmaf(alpha, a0 * rz - x4.x, x4.x);
    float m1 = fmaf(alpha, a1 * rz - x4.y, x4.y);
    float m2 = fmaf(alpha, a2 * rz - x4.z, x4.z);
    float m3 = fmaf(alpha, a3 * rz - x4.w, x4.w);

    float s = (m0 + m1) + (m2 + m3);
    float s2 = fmaf(m0, m0, m1 * m1) + fmaf(m2, m2, m3 * m3);
    #pragma unroll
    for (int d = 32; d >= 1; d >>= 1) {
        s += __shfl_xor(s, d, 64);
        s2 += __shfl_xor(s2, d, 64);
    }
    // both halves duplicated -> divide by 2*DIM
    float mu = s * (1.f / (2 * DIM));
    float var = s2 * (1.f / (2 * DIM)) - mu * mu;
    float rstd = rsqrtf(var + 1e-5f);
    if (hi == 0) {
        float4 g4 = ((const float4*)gmm)[t * 32 + p];
        float4 b4 = ((const float4*)bta)[t * 32 + p];
        float4 o4;
        o4.x = (m0 - mu) * rstd * g4.x + b4.x;
        o4.y = (m1 - mu) * rstd * g4.y + b4.y;
        o4.z = (m2 - mu) * rstd * g4.z + b4.z;
        o4.w = (m3 - mu) * rstd * g4.w + b4.w;
        ((float4*)out)[(size_t)n * 32 + p] = o4;
    }
}

extern "C" void kernel_launch(void* const* d_in, const int* in_sizes, int n_in,
                              void* d_out, int out_size, void* d_ws, size_t ws_size,
                              hipStream_t stream) {
    const float* x      = (const float*)d_in[0];
    const int*   ntype  = (const int*)d_in[1];
    const int*   ei     = (const int*)d_in[2];
    const int*   etype  = (const int*)d_in[3];
    const int*   esign  = (const int*)d_in[4];
    const float* edist  = (const float*)d_in[5];
    const float* Wq     = (const float*)d_in[6];
    const float* bq     = (const float*)d_in[7];
    const float* Wk     = (const float*)d_in[8];
    const float* bk     = (const float*)d_in[9];
    const float* Wv     = (const float*)d_in[10];
    const float* bv     = (const float*)d_in[11];
    const float* rel_q  = (const float*)d_in[12];
    const float* rel_k  = (const float*)d_in[13];
    const float* rel_v  = (const float*)d_in[14];
    const float* skn    = (const float*)d_in[15];
    const float* svn    = (const float*)d_in[16];
    const float* rbias  = (const float*)d_in[17];
    const float* dalpha = (const float*)d_in[18];
    const float* dtau   = (const float*)d_in[19];
    const float* skip   = (const float*)d_in[20];
    const float* gmm    = (const float*)d_in[21];
    const float* bta    = (const float*)d_in[22];
    float* out = (float*)d_out;

    char* ws = (char*)d_ws;
    float*          Qf     = (float*)         (ws + 0);          // 25.6 MB
    unsigned short* KVu    = (unsigned short*)(ws + 25600000);   // 25.6 MB interleaved K/V
    unsigned short* xb     = (unsigned short*)(ws + 51200000);   // 12.8 MB
    unsigned short* Wt     = (unsigned short*)(ws + 64000000);   // 393 KB
    uint4*          wcb    = (uint4*)         (ws + 64500000);   // 12.3 KB
    int*            cnt    = (int*)           (ws + 64600000);   // N
    int*            offs   = (int*)           (ws + 64900000);   // N+1
    int*            bsum   = (int*)           (ws + 65200000);   // 256
    int*            bofs   = (int*)           (ws + 65210000);   // 256
    int*            posw   = (int*)           (ws + 65300000);   // E = 3.2 MB
    int2*           edata  = (int2*)          (ws + 68600000);   // E*8 = 6.4 MB
    int*            opad   = (int*)           (ws + 75000000);   // NPAD_MAX
    int*            bhist  = (int*)           (ws + 75300000);   // 196*4
    int*            bbase  = (int*)           (ws + 75310000);   // 196*4
    int*            pb     = (int*)           (ws + 75320000);   // 5

    // 1. type histogram + zero cnt + init opad (fused memsets)
    k_typehist <<<NBLK_SCAN, 256, 0, stream>>>(ntype, bhist, cnt, opad);
    // 2. type-bucket scan (padded to x16)
    k_typescan <<<1, 1024, 0, stream>>>(bhist, bbase, pb);
    // 3. fused: node scatter | prep (x->bf16, W^T->bf16, bf16 weight table) | edge histogram
    k_mid <<<MID_BLOCKS, 256, 0, stream>>>(ntype, bbase, opad,
                                           x, Wq, Wk, Wv, rel_q, rel_k, rel_v, skn, svn,
                                           xb, Wt, wcb,
                                           ei, cnt, posw);
    // 4. MFMA projection (A-reuse over 6 groups) + scan1 tail blocks
    k_projm <<<NTILE_ROW + NBLK_SCAN, 256, 0, stream>>>(xb, Wt, opad, pb, bq, bk, bv,
                                                        Qf, KVu, cnt, offs, bsum);
    // 5. block-sum scan
    k_scan2 <<<1, 256, 0, stream>>>(bsum, bofs, offs);
    // 6. emit dst-sorted edge records
    k_emit <<<HIST_BLOCKS, 256, 0, stream>>>(ei, etype, esign, edist, dalpha, dtau,
                                             offs, bofs, posw, edata);
    // 7. fused attention + aggregation + skip + LayerNorm
    k_attn <<<N_NODES / 4, 256, 0, stream>>>((const float4*)Qf, (const uint4*)KVu,
                                             (const uint4*)wcb, x, ntype, offs, bofs,
                                             edata, rbias, skip, gmm, bta, out);
}